// Round 1
// baseline (1425.960 us; speedup 1.0000x reference)
//
#include <hip/hip_runtime.h>

#define NCELL 100000
#define NGENE 8000
#define DIM   128
#define NE_CG 1500000
#define NE_GC 1500000
#define NE_CC 1000000
#define NE_GG 200000
#define SLOPE 0.05f
#define LN_EPS 1e-5f

// ---------------- CSR build ----------------
__global__ void hist_kernel(const int* __restrict__ dst, int n, int* __restrict__ deg) {
    int i = blockIdx.x * blockDim.x + threadIdx.x;
    if (i < n) atomicAdd(&deg[dst[i]], 1);
}

__global__ void scan_block_k(const int* __restrict__ in, int* __restrict__ out,
                             int* __restrict__ bsum, int n) {
    __shared__ int sm[256];
    int tid = threadIdx.x;
    int gid = blockIdx.x * 256 + tid;
    int x = (gid < n) ? in[gid] : 0;
    sm[tid] = x;
    __syncthreads();
    for (int ofs = 1; ofs < 256; ofs <<= 1) {
        int t = (tid >= ofs) ? sm[tid - ofs] : 0;
        __syncthreads();
        sm[tid] += t;
        __syncthreads();
    }
    if (gid < n) out[gid] = sm[tid] - x;          // exclusive
    if (tid == 255) bsum[blockIdx.x] = sm[255];   // block total
}

__global__ void scan_top_k(int* __restrict__ bsum, int n) {
    __shared__ int sm[512];
    int tid = threadIdx.x;
    int x = (tid < n) ? bsum[tid] : 0;
    sm[tid] = x;
    __syncthreads();
    for (int ofs = 1; ofs < 512; ofs <<= 1) {
        int t = (tid >= ofs) ? sm[tid - ofs] : 0;
        __syncthreads();
        sm[tid] += t;
        __syncthreads();
    }
    if (tid < n) bsum[tid] = sm[tid] - x;         // exclusive
}

__global__ void scan_add_k(int* __restrict__ out, const int* __restrict__ bsum, int n) {
    int gid = blockIdx.x * 256 + threadIdx.x;
    if (gid < n) out[gid] += bsum[blockIdx.x];
}

__global__ void scatter_k(const int* __restrict__ src, const int* __restrict__ dst, int n,
                          int* __restrict__ cur, int* __restrict__ bkt) {
    int i = blockIdx.x * blockDim.x + threadIdx.x;
    if (i < n) {
        int d = dst[i];
        int slot = atomicAdd(&cur[d], 1);
        bkt[slot] = src[i];
    }
}

// ---------------- per-dst-node pull aggregation ----------------
// One wave per dst node. Relation A fills Acat cols [0,128), relation B cols [128,256),
// each pre-scaled by 1/max(deg,1).
__global__ __launch_bounds__(256)
void gather_k(const float* __restrict__ hA,
              const int* __restrict__ offA, const int* __restrict__ degA,
              const int* __restrict__ bktA,
              const float* __restrict__ hB,
              const int* __restrict__ offB, const int* __restrict__ degB,
              const int* __restrict__ bktB,
              float* __restrict__ Acat, int nDst) {
    int node = blockIdx.x * 4 + (threadIdx.x >> 6);
    if (node >= nDst) return;
    int lane = threadIdx.x & 63;
    float2* outrow = (float2*)(Acat + (size_t)node * 256);
    {
        int s = offA[node], n = degA[node];
        float ax = 0.f, ay = 0.f;
        #pragma unroll 4
        for (int j = 0; j < n; ++j) {
            int sidx = bktA[s + j];
            float2 v = ((const float2*)(hA + (size_t)sidx * DIM))[lane];
            ax += v.x; ay += v.y;
        }
        float inv = 1.0f / fmaxf((float)n, 1.0f);
        outrow[lane] = make_float2(ax * inv, ay * inv);
    }
    {
        int s = offB[node], n = degB[node];
        float ax = 0.f, ay = 0.f;
        #pragma unroll 4
        for (int j = 0; j < n; ++j) {
            int sidx = bktB[s + j];
            float2 v = ((const float2*)(hB + (size_t)sidx * DIM))[lane];
            ax += v.x; ay += v.y;
        }
        float inv = 1.0f / fmaxf((float)n, 1.0f);
        outrow[64 + lane] = make_float2(ax * inv, ay * inv);
    }
}

// ---------------- fused 2-relation GEMM: C = A[M,256] @ [W1;W2] + b, LeakyReLU ----------------
#define BM 64
#define BN 128
#define BK 32

__global__ __launch_bounds__(256)
void gemm_k(const float* __restrict__ A,    // [M][256]
            const float* __restrict__ W1,   // [128][128], k in [0,128)
            const float* __restrict__ W2,   // [128][128], k in [128,256)
            const float* __restrict__ bias, // [128]
            float* __restrict__ Cout,       // [M][128]
            int M) {
    __shared__ float Ast[BK][BM];   // A tile, transposed
    __shared__ float Ws[BK][BN];
    int tid = threadIdx.x;
    int tx = tid & 15;   // 16 col groups: cols tx*4..+3 and 64+tx*4..+3
    int ty = tid >> 4;   // 16 row groups: rows ty*4..+3
    int m0 = blockIdx.x * BM;

    float acc[4][8];
    #pragma unroll
    for (int r = 0; r < 4; ++r)
        #pragma unroll
        for (int c = 0; c < 8; ++c) acc[r][c] = 0.f;

    for (int kt = 0; kt < 256; kt += BK) {
        // stage A tile: 64 rows x 32 cols -> Ast[k][m]
        #pragma unroll
        for (int l = tid; l < 512; l += 256) {
            int row = l >> 3;
            int c4  = l & 7;
            float4 v = make_float4(0.f, 0.f, 0.f, 0.f);
            if (m0 + row < M)
                v = *(const float4*)(A + (size_t)(m0 + row) * 256 + kt + c4 * 4);
            Ast[c4 * 4 + 0][row] = v.x;
            Ast[c4 * 4 + 1][row] = v.y;
            Ast[c4 * 4 + 2][row] = v.z;
            Ast[c4 * 4 + 3][row] = v.w;
        }
        // stage W tile: 32 rows x 128 cols
        const float* Wp = (kt < 128) ? (W1 + (size_t)kt * 128) : (W2 + (size_t)(kt - 128) * 128);
        #pragma unroll
        for (int l = tid; l < 1024; l += 256) {
            int row = l >> 5;
            int c4  = l & 31;
            *(float4*)(&Ws[row][c4 * 4]) = *(const float4*)(Wp + (size_t)row * 128 + c4 * 4);
        }
        __syncthreads();
        #pragma unroll
        for (int k = 0; k < BK; ++k) {
            float4 av = *(const float4*)(&Ast[k][ty * 4]);
            float4 w0 = *(const float4*)(&Ws[k][tx * 4]);
            float4 w1 = *(const float4*)(&Ws[k][64 + tx * 4]);
            float a[4] = {av.x, av.y, av.z, av.w};
            float w[8] = {w0.x, w0.y, w0.z, w0.w, w1.x, w1.y, w1.z, w1.w};
            #pragma unroll
            for (int r = 0; r < 4; ++r)
                #pragma unroll
                for (int c = 0; c < 8; ++c)
                    acc[r][c] += a[r] * w[c];
        }
        __syncthreads();
    }
    // epilogue: bias + LeakyReLU
    float4 bA = *(const float4*)(bias + tx * 4);
    float4 bB = *(const float4*)(bias + 64 + tx * 4);
    #pragma unroll
    for (int r = 0; r < 4; ++r) {
        int row = m0 + ty * 4 + r;
        if (row < M) {
            float o[8];
            o[0] = acc[r][0] + bA.x; o[1] = acc[r][1] + bA.y;
            o[2] = acc[r][2] + bA.z; o[3] = acc[r][3] + bA.w;
            o[4] = acc[r][4] + bB.x; o[5] = acc[r][5] + bB.y;
            o[6] = acc[r][6] + bB.z; o[7] = acc[r][7] + bB.w;
            #pragma unroll
            for (int c = 0; c < 8; ++c) o[c] = (o[c] >= 0.f) ? o[c] : SLOPE * o[c];
            *(float4*)(Cout + (size_t)row * 128 + tx * 4)      = make_float4(o[0], o[1], o[2], o[3]);
            *(float4*)(Cout + (size_t)row * 128 + 64 + tx * 4) = make_float4(o[4], o[5], o[6], o[7]);
        }
    }
}

// ---------------- in-place LayerNorm over rows of [NCELL+NGENE][128] ----------------
__global__ __launch_bounds__(256)
void ln_k(float* __restrict__ out,
          const float* __restrict__ s_cell, const float* __restrict__ b_cell,
          const float* __restrict__ s_gene, const float* __restrict__ b_gene) {
    int row = blockIdx.x * 4 + (threadIdx.x >> 6);
    if (row >= NCELL + NGENE) return;
    int lane = threadIdx.x & 63;
    float2* p = (float2*)(out + (size_t)row * DIM);
    float2 v = p[lane];
    float sum = v.x + v.y;
    float sq  = v.x * v.x + v.y * v.y;
    #pragma unroll
    for (int ofs = 32; ofs >= 1; ofs >>= 1) {
        sum += __shfl_xor(sum, ofs);
        sq  += __shfl_xor(sq, ofs);
    }
    float mu  = sum * (1.0f / 128.0f);
    float var = sq * (1.0f / 128.0f) - mu * mu;
    float rstd = rsqrtf(var + LN_EPS);
    const float* sc = (row < NCELL) ? s_cell : s_gene;
    const float* bc = (row < NCELL) ? b_cell : b_gene;
    float sx = sc[lane * 2], sy = sc[lane * 2 + 1];
    float bx = bc[lane * 2], by = bc[lane * 2 + 1];
    p[lane] = make_float2((v.x - mu) * rstd * sx + bx, (v.y - mu) * rstd * sy + by);
}

extern "C" void kernel_launch(void* const* d_in, const int* in_sizes, int n_in,
                              void* d_out, int out_size, void* d_ws, size_t ws_size,
                              hipStream_t stream) {
    const float* h_cell = (const float*)d_in[0];
    const float* h_gene = (const float*)d_in[1];
    const int* src_cg = (const int*)d_in[2];
    const int* dst_cg = (const int*)d_in[3];
    const int* src_gc = (const int*)d_in[4];
    const int* dst_gc = (const int*)d_in[5];
    const int* src_cc = (const int*)d_in[6];
    const int* dst_cc = (const int*)d_in[7];
    const int* src_gg = (const int*)d_in[8];
    const int* dst_gg = (const int*)d_in[9];
    const float* W_cg = (const float*)d_in[10];
    const float* W_gc = (const float*)d_in[11];
    const float* W_cc = (const float*)d_in[12];
    const float* W_gg = (const float*)d_in[13];
    const float* b_cell = (const float*)d_in[14];
    const float* b_gene = (const float*)d_in[15];
    const float* ln_s_cell = (const float*)d_in[16];
    const float* ln_b_cell = (const float*)d_in[17];
    const float* ln_s_gene = (const float*)d_in[18];
    const float* ln_b_gene = (const float*)d_in[19];
    float* out = (float*)d_out;

    char* wsb = (char*)d_ws;
    size_t off = 0;
    auto alloc = [&](size_t bytes) -> char* {
        char* p = wsb + off;
        off = (off + bytes + 255) & ~(size_t)255;
        return p;
    };
    float* Acat_c = (float*)alloc((size_t)NCELL * 256 * 4);
    float* Acat_g = (float*)alloc((size_t)NGENE * 256 * 4);
    int ndeg = 2 * NCELL + 2 * NGENE;
    int* degs = (int*)alloc((size_t)ndeg * 4);
    int* deg_gc = degs;
    int* deg_cc = degs + NCELL;
    int* deg_cg = degs + 2 * NCELL;
    int* deg_gg = degs + 2 * NCELL + NGENE;
    int* offs = (int*)alloc((size_t)ndeg * 4);
    int* off_gc = offs;
    int* off_cc = offs + NCELL;
    int* off_cg = offs + 2 * NCELL;
    int* off_gg = offs + 2 * NCELL + NGENE;
    int* curs = (int*)alloc((size_t)ndeg * 4);
    int* cur_gc = curs;
    int* cur_cc = curs + NCELL;
    int* cur_cg = curs + 2 * NCELL;
    int* cur_gg = curs + 2 * NCELL + NGENE;
    int* bkt_gc = (int*)alloc((size_t)NE_GC * 4);
    int* bkt_cc = (int*)alloc((size_t)NE_CC * 4);
    int* bkt_cg = (int*)alloc((size_t)NE_CG * 4);
    int* bkt_gg = (int*)alloc((size_t)NE_GG * 4);
    int* bsum = (int*)alloc(4096);

    // ---- CSR build (indices are identical for both layers; built once per launch) ----
    hipMemsetAsync(degs, 0, (size_t)ndeg * 4, stream);
    hist_kernel<<<(NE_GC + 255) / 256, 256, 0, stream>>>(dst_gc, NE_GC, deg_gc);
    hist_kernel<<<(NE_CC + 255) / 256, 256, 0, stream>>>(dst_cc, NE_CC, deg_cc);
    hist_kernel<<<(NE_CG + 255) / 256, 256, 0, stream>>>(dst_cg, NE_CG, deg_cg);
    hist_kernel<<<(NE_GG + 255) / 256, 256, 0, stream>>>(dst_gg, NE_GG, deg_gg);

    auto scan = [&](const int* in, int* out_, int n) {
        int nb = (n + 255) / 256;
        scan_block_k<<<nb, 256, 0, stream>>>(in, out_, bsum, n);
        scan_top_k<<<1, 512, 0, stream>>>(bsum, nb);
        scan_add_k<<<nb, 256, 0, stream>>>(out_, bsum, n);
    };
    scan(deg_gc, off_gc, NCELL);
    scan(deg_cc, off_cc, NCELL);
    scan(deg_cg, off_cg, NGENE);
    scan(deg_gg, off_gg, NGENE);

    hipMemcpyAsync(curs, offs, (size_t)ndeg * 4, hipMemcpyDeviceToDevice, stream);
    scatter_k<<<(NE_GC + 255) / 256, 256, 0, stream>>>(src_gc, dst_gc, NE_GC, cur_gc, bkt_gc);
    scatter_k<<<(NE_CC + 255) / 256, 256, 0, stream>>>(src_cc, dst_cc, NE_CC, cur_cc, bkt_cc);
    scatter_k<<<(NE_CG + 255) / 256, 256, 0, stream>>>(src_cg, dst_cg, NE_CG, cur_cg, bkt_cg);
    scatter_k<<<(NE_GG + 255) / 256, 256, 0, stream>>>(src_gg, dst_gg, NE_GG, cur_gg, bkt_gg);

    // ---- two shared layers; layer-1 activations live in d_out ----
    const float* hc = h_cell;
    const float* hg = h_gene;
    float* out_c = out;
    float* out_g = out + (size_t)NCELL * DIM;
    for (int layer = 0; layer < 2; ++layer) {
        gather_k<<<(NCELL + 3) / 4, 256, 0, stream>>>(hg, off_gc, deg_gc, bkt_gc,
                                                      hc, off_cc, deg_cc, bkt_cc,
                                                      Acat_c, NCELL);
        gather_k<<<(NGENE + 3) / 4, 256, 0, stream>>>(hc, off_cg, deg_cg, bkt_cg,
                                                      hg, off_gg, deg_gg, bkt_gg,
                                                      Acat_g, NGENE);
        gemm_k<<<(NCELL + BM - 1) / BM, 256, 0, stream>>>(Acat_c, W_gc, W_cc, b_cell, out_c, NCELL);
        gemm_k<<<(NGENE + BM - 1) / BM, 256, 0, stream>>>(Acat_g, W_cg, W_gg, b_gene, out_g, NGENE);
        ln_k<<<((NCELL + NGENE) + 3) / 4, 256, 0, stream>>>(out, ln_s_cell, ln_b_cell,
                                                            ln_s_gene, ln_b_gene);
        hc = out_c;
        hg = out_g;
    }
}

// Round 2
// 1015.640 us; speedup vs baseline: 1.4040x; 1.4040x over previous
//
#include <hip/hip_runtime.h>
#include <hip/hip_bf16.h>

#define NCELL 100000
#define NGENE 8000
#define DIM   128
#define NE_CG 1500000
#define NE_GC 1500000
#define NE_CC 1000000
#define NE_GG 200000
#define SLOPE 0.05f
#define LN_EPS 1e-5f

typedef __attribute__((ext_vector_type(8))) short bf16x8;
typedef __attribute__((ext_vector_type(4))) float f32x4;

__device__ __forceinline__ float bflo(unsigned v) { return __uint_as_float(v << 16); }
__device__ __forceinline__ float bfhi(unsigned v) { return __uint_as_float(v & 0xffff0000u); }
__device__ __forceinline__ unsigned short f2bf(float x) {
    union { float f; unsigned u; } a; a.f = x;
    unsigned r = a.u + 0x7fffu + ((a.u >> 16) & 1u);   // round-to-nearest-even
    return (unsigned short)(r >> 16);
}
__device__ __forceinline__ unsigned pack2(float x, float y) {
    return (unsigned)f2bf(x) | ((unsigned)f2bf(y) << 16);
}

// ---------------- f32 -> bf16 table conversion ----------------
__global__ __launch_bounds__(256)
void conv_bf16_k(const float* __restrict__ in, unsigned short* __restrict__ out, int n2) {
    int i = blockIdx.x * 256 + threadIdx.x;
    if (i < n2) {
        float2 v = ((const float2*)in)[i];
        ((unsigned*)out)[i] = pack2(v.x, v.y);
    }
}

// ---------------- pack [W1;W2] (f32, row-major [128][128] each) into MFMA B-frag layout ----
// Wp[(t*8+c)*64 + lane][8]: element j -> B[k = c*32 + (lane>>4)*8 + j][n = t*16 + (lane&15)]
__global__ void pack_w_k(const float* __restrict__ WA, const float* __restrict__ WB,
                         unsigned short* __restrict__ Wp) {
    int b = blockIdx.x;       // t*8 + c, 64 blocks
    int lane = threadIdx.x;   // 64 threads
    int t = b >> 3, c = b & 7;
    int n = t * 16 + (lane & 15);
    int k0 = c * 32 + (lane >> 4) * 8;
    #pragma unroll
    for (int j = 0; j < 8; ++j) {
        int k = k0 + j;
        float x = (k < 128) ? WA[k * 128 + n] : WB[(k - 128) * 128 + n];
        Wp[((size_t)(b * 64 + lane)) * 8 + j] = f2bf(x);
    }
}

// ---------------- CSR build ----------------
__global__ void hist_kernel(const int* __restrict__ dst, int n, int* __restrict__ deg) {
    int i = blockIdx.x * blockDim.x + threadIdx.x;
    if (i < n) atomicAdd(&deg[dst[i]], 1);
}

__global__ void scan_block_k(const int* __restrict__ in, int* __restrict__ out,
                             int* __restrict__ bsum, int n) {
    __shared__ int sm[256];
    int tid = threadIdx.x;
    int gid = blockIdx.x * 256 + tid;
    int x = (gid < n) ? in[gid] : 0;
    sm[tid] = x;
    __syncthreads();
    for (int ofs = 1; ofs < 256; ofs <<= 1) {
        int t = (tid >= ofs) ? sm[tid - ofs] : 0;
        __syncthreads();
        sm[tid] += t;
        __syncthreads();
    }
    if (gid < n) out[gid] = sm[tid] - x;
    if (tid == 255) bsum[blockIdx.x] = sm[255];
}

__global__ void scan_top_k(int* __restrict__ bsum, int n) {
    __shared__ int sm[512];
    int tid = threadIdx.x;
    int x = (tid < n) ? bsum[tid] : 0;
    sm[tid] = x;
    __syncthreads();
    for (int ofs = 1; ofs < 512; ofs <<= 1) {
        int t = (tid >= ofs) ? sm[tid - ofs] : 0;
        __syncthreads();
        sm[tid] += t;
        __syncthreads();
    }
    if (tid < n) bsum[tid] = sm[tid] - x;
}

__global__ void scan_add_k(int* __restrict__ out, const int* __restrict__ bsum, int n) {
    int gid = blockIdx.x * 256 + threadIdx.x;
    if (gid < n) out[gid] += bsum[blockIdx.x];
}

__global__ void scatter_k(const int* __restrict__ src, const int* __restrict__ dst, int n,
                          int* __restrict__ cur, int* __restrict__ bkt) {
    int i = blockIdx.x * blockDim.x + threadIdx.x;
    if (i < n) {
        int d = dst[i];
        int slot = atomicAdd(&cur[d], 1);
        bkt[slot] = src[i];
    }
}

// ---------------- per-dst-node pull aggregation (bf16 rows, f32 accum, bf16 out) --------
__global__ __launch_bounds__(256)
void gather_k(const unsigned short* __restrict__ hA,
              const int* __restrict__ offA, const int* __restrict__ degA,
              const int* __restrict__ bktA,
              const unsigned short* __restrict__ hB,
              const int* __restrict__ offB, const int* __restrict__ degB,
              const int* __restrict__ bktB,
              unsigned short* __restrict__ Acat, int nDst) {
    int node = blockIdx.x * 4 + (threadIdx.x >> 6);
    if (node >= nDst) return;
    int lane = threadIdx.x & 63;
    unsigned* outrow = (unsigned*)(Acat + (size_t)node * 256);
    {
        int s = offA[node], n = degA[node];
        float ax = 0.f, ay = 0.f;
        #pragma unroll 4
        for (int j = 0; j < n; ++j) {
            int sidx = bktA[s + j];
            unsigned v = ((const unsigned*)(hA + (size_t)sidx * DIM))[lane];
            ax += bflo(v); ay += bfhi(v);
        }
        float inv = 1.0f / fmaxf((float)n, 1.0f);
        outrow[lane] = pack2(ax * inv, ay * inv);
    }
    {
        int s = offB[node], n = degB[node];
        float ax = 0.f, ay = 0.f;
        #pragma unroll 4
        for (int j = 0; j < n; ++j) {
            int sidx = bktB[s + j];
            unsigned v = ((const unsigned*)(hB + (size_t)sidx * DIM))[lane];
            ax += bflo(v); ay += bfhi(v);
        }
        float inv = 1.0f / fmaxf((float)n, 1.0f);
        outrow[64 + lane] = pack2(ax * inv, ay * inv);
    }
}

// ---------------- MFMA GEMM [M,256]bf16 @ [256,128]bf16 + bias + LeakyReLU + LN ----------
// Block: 256 thr = 4 waves, each wave 32 rows x 128 cols (2 m-tiles x 8 n-tiles, 16x16x32).
// W fragments staged in LDS (64 KB); A fragments loaded straight from global (16B contig).
#define GBM 128
__global__ __launch_bounds__(256)
void gemm_ln_k(const unsigned short* __restrict__ A,   // [Mpad][256] bf16
               const unsigned short* __restrict__ Wp,  // packed frags, 64 KB
               const float* __restrict__ bias,
               const float* __restrict__ lns, const float* __restrict__ lnb,
               unsigned short* __restrict__ outh,      // bf16 table (layer 1) or null
               float* __restrict__ outf,               // f32 final (layer 2) or null
               int M) {
    __shared__ unsigned short Ws[32768];  // 64 KB
    int tid = threadIdx.x;
    {
        const uint4* s = (const uint4*)Wp;
        uint4* d = (uint4*)Ws;
        #pragma unroll
        for (int i = tid; i < 4096; i += 256) d[i] = s[i];
    }
    __syncthreads();

    int wave = tid >> 6, lane = tid & 63;
    int col0 = lane & 15;       // col within 16-tile; also A-row within 16-tile
    int kq = lane >> 4;         // k-quad for A/B frags; row-quad for C/D
    int m_base = blockIdx.x * GBM + wave * 32;

    f32x4 acc[2][8];
    #pragma unroll
    for (int mt = 0; mt < 2; ++mt)
        #pragma unroll
        for (int t = 0; t < 8; ++t) acc[mt][t] = (f32x4){0.f, 0.f, 0.f, 0.f};

    const unsigned short* Ar0 = A + (size_t)(m_base + col0) * 256 + kq * 8;
    const unsigned short* Ar1 = Ar0 + 16 * 256;
    #pragma unroll
    for (int c = 0; c < 8; ++c) {
        bf16x8 a0 = *(const bf16x8*)(Ar0 + c * 32);
        bf16x8 a1 = *(const bf16x8*)(Ar1 + c * 32);
        #pragma unroll
        for (int t = 0; t < 8; ++t) {
            bf16x8 b = *(const bf16x8*)(Ws + ((t * 8 + c) * 64 + lane) * 8);
            acc[0][t] = __builtin_amdgcn_mfma_f32_16x16x32_bf16(a0, b, acc[0][t], 0, 0, 0);
            acc[1][t] = __builtin_amdgcn_mfma_f32_16x16x32_bf16(a1, b, acc[1][t], 0, 0, 0);
        }
    }

    // epilogue: bias + LeakyReLU + LayerNorm, all in-register
    float bias_r[8], s_r[8], b_r[8];
    #pragma unroll
    for (int t = 0; t < 8; ++t) {
        int col = t * 16 + col0;
        bias_r[t] = bias[col]; s_r[t] = lns[col]; b_r[t] = lnb[col];
    }
    #pragma unroll
    for (int mt = 0; mt < 2; ++mt) {
        #pragma unroll
        for (int r = 0; r < 4; ++r) {
            int row = m_base + mt * 16 + kq * 4 + r;   // C/D: row=(lane>>4)*4+reg
            float v[8]; float sum = 0.f, sq = 0.f;
            #pragma unroll
            for (int t = 0; t < 8; ++t) {
                float x = acc[mt][t][r] + bias_r[t];
                x = (x >= 0.f) ? x : SLOPE * x;
                v[t] = x; sum += x; sq += x * x;
            }
            #pragma unroll
            for (int ofs = 1; ofs <= 8; ofs <<= 1) {
                sum += __shfl_xor(sum, ofs);
                sq  += __shfl_xor(sq, ofs);
            }
            float mu = sum * (1.0f / 128.0f);
            float var = sq * (1.0f / 128.0f) - mu * mu;
            float rstd = rsqrtf(var + LN_EPS);
            if (row < M) {
                if (outh) {
                    #pragma unroll
                    for (int t = 0; t < 8; ++t)
                        outh[(size_t)row * 128 + t * 16 + col0] =
                            f2bf((v[t] - mu) * rstd * s_r[t] + b_r[t]);
                } else {
                    #pragma unroll
                    for (int t = 0; t < 8; ++t)
                        outf[(size_t)row * 128 + t * 16 + col0] =
                            (v[t] - mu) * rstd * s_r[t] + b_r[t];
                }
            }
        }
    }
}

extern "C" void kernel_launch(void* const* d_in, const int* in_sizes, int n_in,
                              void* d_out, int out_size, void* d_ws, size_t ws_size,
                              hipStream_t stream) {
    const float* h_cell = (const float*)d_in[0];
    const float* h_gene = (const float*)d_in[1];
    const int* src_cg = (const int*)d_in[2];
    const int* dst_cg = (const int*)d_in[3];
    const int* src_gc = (const int*)d_in[4];
    const int* dst_gc = (const int*)d_in[5];
    const int* src_cc = (const int*)d_in[6];
    const int* dst_cc = (const int*)d_in[7];
    const int* src_gg = (const int*)d_in[8];
    const int* dst_gg = (const int*)d_in[9];
    const float* W_cg = (const float*)d_in[10];
    const float* W_gc = (const float*)d_in[11];
    const float* W_cc = (const float*)d_in[12];
    const float* W_gg = (const float*)d_in[13];
    const float* b_cell = (const float*)d_in[14];
    const float* b_gene = (const float*)d_in[15];
    const float* ln_s_cell = (const float*)d_in[16];
    const float* ln_b_cell = (const float*)d_in[17];
    const float* ln_s_gene = (const float*)d_in[18];
    const float* ln_b_gene = (const float*)d_in[19];
    float* out = (float*)d_out;

    const int MPC = ((NCELL + GBM - 1) / GBM) * GBM;  // 100096
    const int MPG = ((NGENE + GBM - 1) / GBM) * GBM;  // 8064

    char* wsb = (char*)d_ws;
    size_t off = 0;
    auto alloc = [&](size_t bytes) -> char* {
        char* p = wsb + off;
        off = (off + bytes + 255) & ~(size_t)255;
        return p;
    };
    unsigned short* Acat_c = (unsigned short*)alloc((size_t)MPC * 256 * 2);
    unsigned short* Acat_g = (unsigned short*)alloc((size_t)MPG * 256 * 2);
    unsigned short* hcb0 = (unsigned short*)alloc((size_t)NCELL * DIM * 2);
    unsigned short* hgb0 = (unsigned short*)alloc((size_t)NGENE * DIM * 2);
    unsigned short* hcb1 = (unsigned short*)alloc((size_t)NCELL * DIM * 2);
    unsigned short* hgb1 = (unsigned short*)alloc((size_t)NGENE * DIM * 2);
    unsigned short* Wp_cell = (unsigned short*)alloc(65536);
    unsigned short* Wp_gene = (unsigned short*)alloc(65536);
    int ndeg = 2 * NCELL + 2 * NGENE;
    int* degs = (int*)alloc((size_t)ndeg * 4);
    int* deg_gc = degs;
    int* deg_cc = degs + NCELL;
    int* deg_cg = degs + 2 * NCELL;
    int* deg_gg = degs + 2 * NCELL + NGENE;
    int* offs = (int*)alloc((size_t)ndeg * 4);
    int* off_gc = offs;
    int* off_cc = offs + NCELL;
    int* off_cg = offs + 2 * NCELL;
    int* off_gg = offs + 2 * NCELL + NGENE;
    int* curs = (int*)alloc((size_t)ndeg * 4);
    int* cur_gc = curs;
    int* cur_cc = curs + NCELL;
    int* cur_cg = curs + 2 * NCELL;
    int* cur_gg = curs + 2 * NCELL + NGENE;
    int* bkt_gc = (int*)alloc((size_t)NE_GC * 4);
    int* bkt_cc = (int*)alloc((size_t)NE_CC * 4);
    int* bkt_cg = (int*)alloc((size_t)NE_CG * 4);
    int* bkt_gg = (int*)alloc((size_t)NE_GG * 4);
    int* bsum = (int*)alloc(4096);

    // ---- input conversion + weight packing ----
    conv_bf16_k<<<(NCELL * DIM / 2 + 255) / 256, 256, 0, stream>>>(h_cell, hcb0, NCELL * DIM / 2);
    conv_bf16_k<<<(NGENE * DIM / 2 + 255) / 256, 256, 0, stream>>>(h_gene, hgb0, NGENE * DIM / 2);
    pack_w_k<<<64, 64, 0, stream>>>(W_gc, W_cc, Wp_cell);  // cell dst: k<128 from gc, else cc
    pack_w_k<<<64, 64, 0, stream>>>(W_cg, W_gg, Wp_gene);  // gene dst: k<128 from cg, else gg

    // ---- CSR build ----
    hipMemsetAsync(degs, 0, (size_t)ndeg * 4, stream);
    hist_kernel<<<(NE_GC + 255) / 256, 256, 0, stream>>>(dst_gc, NE_GC, deg_gc);
    hist_kernel<<<(NE_CC + 255) / 256, 256, 0, stream>>>(dst_cc, NE_CC, deg_cc);
    hist_kernel<<<(NE_CG + 255) / 256, 256, 0, stream>>>(dst_cg, NE_CG, deg_cg);
    hist_kernel<<<(NE_GG + 255) / 256, 256, 0, stream>>>(dst_gg, NE_GG, deg_gg);

    auto scan = [&](const int* in, int* out_, int n) {
        int nb = (n + 255) / 256;
        scan_block_k<<<nb, 256, 0, stream>>>(in, out_, bsum, n);
        scan_top_k<<<1, 512, 0, stream>>>(bsum, nb);
        scan_add_k<<<nb, 256, 0, stream>>>(out_, bsum, n);
    };
    scan(deg_gc, off_gc, NCELL);
    scan(deg_cc, off_cc, NCELL);
    scan(deg_cg, off_cg, NGENE);
    scan(deg_gg, off_gg, NGENE);

    hipMemcpyAsync(curs, offs, (size_t)ndeg * 4, hipMemcpyDeviceToDevice, stream);
    scatter_k<<<(NE_GC + 255) / 256, 256, 0, stream>>>(src_gc, dst_gc, NE_GC, cur_gc, bkt_gc);
    scatter_k<<<(NE_CC + 255) / 256, 256, 0, stream>>>(src_cc, dst_cc, NE_CC, cur_cc, bkt_cc);
    scatter_k<<<(NE_CG + 255) / 256, 256, 0, stream>>>(src_cg, dst_cg, NE_CG, cur_cg, bkt_cg);
    scatter_k<<<(NE_GG + 255) / 256, 256, 0, stream>>>(src_gg, dst_gg, NE_GG, cur_gg, bkt_gg);

    // ---- two shared layers ----
    const unsigned short* hc = hcb0;
    const unsigned short* hg = hgb0;
    for (int layer = 0; layer < 2; ++layer) {
        int final_ = (layer == 1);
        gather_k<<<(NCELL + 3) / 4, 256, 0, stream>>>(hg, off_gc, deg_gc, bkt_gc,
                                                      hc, off_cc, deg_cc, bkt_cc,
                                                      Acat_c, NCELL);
        gather_k<<<(NGENE + 3) / 4, 256, 0, stream>>>(hc, off_cg, deg_cg, bkt_cg,
                                                      hg, off_gg, deg_gg, bkt_gg,
                                                      Acat_g, NGENE);
        gemm_ln_k<<<MPC / GBM, 256, 0, stream>>>(Acat_c, Wp_cell, b_cell, ln_s_cell, ln_b_cell,
                                                 final_ ? nullptr : hcb1,
                                                 final_ ? out : nullptr, NCELL);
        gemm_ln_k<<<MPG / GBM, 256, 0, stream>>>(Acat_g, Wp_gene, b_gene, ln_s_gene, ln_b_gene,
                                                 final_ ? nullptr : hgb1,
                                                 final_ ? out + (size_t)NCELL * DIM : nullptr, NGENE);
        hc = hcb1;
        hg = hgb1;
    }
}

// Round 3
// 764.401 us; speedup vs baseline: 1.8655x; 1.3287x over previous
//
#include <hip/hip_runtime.h>
#include <hip/hip_bf16.h>

#define NCELL 100000
#define NGENE 8000
#define DIM   128
#define NE_CG 1500000
#define NE_GC 1500000
#define NE_CC 1000000
#define NE_GG 200000
#define SLOPE 0.05f
#define LN_EPS 1e-5f

typedef __attribute__((ext_vector_type(8))) short bf16x8;
typedef __attribute__((ext_vector_type(4))) float f32x4;

__device__ __forceinline__ float bflo(unsigned v) { return __uint_as_float(v << 16); }
__device__ __forceinline__ float bfhi(unsigned v) { return __uint_as_float(v & 0xffff0000u); }
__device__ __forceinline__ unsigned short f2bf(float x) {
    union { float f; unsigned u; } a; a.f = x;
    unsigned r = a.u + 0x7fffu + ((a.u >> 16) & 1u);   // round-to-nearest-even
    return (unsigned short)(r >> 16);
}
__device__ __forceinline__ unsigned pack2(float x, float y) {
    return (unsigned)f2bf(x) | ((unsigned)f2bf(y) << 16);
}

// ---------------- f32 -> bf16 table conversion ----------------
__global__ __launch_bounds__(256)
void conv_bf16_k(const float* __restrict__ in, unsigned short* __restrict__ out, int n2) {
    int i = blockIdx.x * 256 + threadIdx.x;
    if (i < n2) {
        float2 v = ((const float2*)in)[i];
        ((unsigned*)out)[i] = pack2(v.x, v.y);
    }
}

// ---------------- pack [W1;W2] into MFMA B-frag layout ----------------
__global__ void pack_w_k(const float* __restrict__ WA, const float* __restrict__ WB,
                         unsigned short* __restrict__ Wp) {
    int b = blockIdx.x;       // t*8 + c
    int lane = threadIdx.x;   // 64
    int t = b >> 3, c = b & 7;
    int n = t * 16 + (lane & 15);
    int k0 = c * 32 + (lane >> 4) * 8;
    #pragma unroll
    for (int j = 0; j < 8; ++j) {
        int k = k0 + j;
        float x = (k < 128) ? WA[k * 128 + n] : WB[(k - 128) * 128 + n];
        Wp[((size_t)(b * 64 + lane)) * 8 + j] = f2bf(x);
    }
}

// ================= binned CSR build =================
// bin = dst >> shift (cell-dst: shift=8 -> 391 bins; gene-dst: shift=4 -> 500 bins)
// staging element: src | (dst_local << 20)   (src<=17 bits, dst_local<=8 bits)

__global__ __launch_bounds__(256)
void bin_count_k(const int* __restrict__ dst, int n, int shift, int* __restrict__ bcnt) {
    __shared__ int cnt[512];
    int tid = threadIdx.x;
    cnt[tid] = 0; cnt[tid + 256] = 0;
    __syncthreads();
    int base = blockIdx.x * 4096;
    #pragma unroll
    for (int it = 0; it < 16; ++it) {
        int i = base + it * 256 + tid;
        if (i < n) atomicAdd(&cnt[dst[i] >> shift], 1);
    }
    __syncthreads();
    if (cnt[tid])       atomicAdd(&bcnt[tid], cnt[tid]);
    if (cnt[tid + 256]) atomicAdd(&bcnt[tid + 256], cnt[tid + 256]);
}

__global__ __launch_bounds__(512)
void bin_scan_k(const int* __restrict__ bcnt, int* __restrict__ boff,
                int* __restrict__ bcur, int nbins) {
    __shared__ int sm[512];
    int tid = threadIdx.x;
    int x = (tid < nbins) ? bcnt[tid] : 0;
    sm[tid] = x;
    __syncthreads();
    for (int ofs = 1; ofs < 512; ofs <<= 1) {
        int t = (tid >= ofs) ? sm[tid - ofs] : 0;
        __syncthreads();
        sm[tid] += t;
        __syncthreads();
    }
    int excl = sm[tid] - x;
    if (tid < nbins) { boff[tid] = excl; bcur[tid] = excl; }
    if (tid == 511) boff[nbins] = sm[511];
}

__global__ __launch_bounds__(256)
void bin_fill_k(const int* __restrict__ src, const int* __restrict__ dst, int n, int shift,
                int* __restrict__ bcur, unsigned* __restrict__ stg) {
    __shared__ int cnt[512];
    __shared__ int basem[512];
    int tid = threadIdx.x;
    cnt[tid] = 0; cnt[tid + 256] = 0;
    __syncthreads();
    int base = blockIdx.x * 4096;
    int bins[16]; int ranks[16]; unsigned pk[16];
    #pragma unroll
    for (int it = 0; it < 16; ++it) {
        int i = base + it * 256 + tid;
        bins[it] = -1;
        if (i < n) {
            int d = dst[i];
            int bn = d >> shift;
            int dl = d & ((1 << shift) - 1);
            bins[it] = bn;
            pk[it] = (unsigned)src[i] | ((unsigned)dl << 20);
            ranks[it] = atomicAdd(&cnt[bn], 1);
        }
    }
    __syncthreads();
    if (cnt[tid])       basem[tid]       = atomicAdd(&bcur[tid],       cnt[tid]);
    if (cnt[tid + 256]) basem[tid + 256] = atomicAdd(&bcur[tid + 256], cnt[tid + 256]);
    __syncthreads();
    #pragma unroll
    for (int it = 0; it < 16; ++it)
        if (bins[it] >= 0) stg[basem[bins[it]] + ranks[it]] = pk[it];
}

__global__ __launch_bounds__(256)
void bin_csr_k(const unsigned* __restrict__ stg, const int* __restrict__ boff,
               int shift, int N,
               int* __restrict__ degg, int* __restrict__ offg, int* __restrict__ bkt) {
    int b = blockIdx.x, tid = threadIdx.x;
    int e0 = boff[b], e1 = boff[b + 1];
    __shared__ int deg[256];
    __shared__ int sc[256];
    __shared__ int cur[256];
    deg[tid] = 0;
    __syncthreads();
    for (int i = e0 + tid; i < e1; i += 256)
        atomicAdd(&deg[(stg[i] >> 20) & 255], 1);
    __syncthreads();
    int x = deg[tid];
    sc[tid] = x;
    __syncthreads();
    for (int ofs = 1; ofs < 256; ofs <<= 1) {
        int t = (tid >= ofs) ? sc[tid - ofs] : 0;
        __syncthreads();
        sc[tid] += t;
        __syncthreads();
    }
    int excl = sc[tid] - x;
    cur[tid] = excl;
    int node = (b << shift) + tid;
    if (tid < (1 << shift) && node < N) { degg[node] = x; offg[node] = e0 + excl; }
    __syncthreads();
    for (int i = e0 + tid; i < e1; i += 256) {
        unsigned p = stg[i];
        int dl = (p >> 20) & 255;
        int r = atomicAdd(&cur[dl], 1);
        bkt[e0 + r] = (int)(p & 0xFFFFFu);
    }
}

// ---------------- per-dst-node pull aggregation (bf16 rows, f32 accum, bf16 out) --------
__global__ __launch_bounds__(256)
void gather_k(const unsigned short* __restrict__ hA,
              const int* __restrict__ offA, const int* __restrict__ degA,
              const int* __restrict__ bktA,
              const unsigned short* __restrict__ hB,
              const int* __restrict__ offB, const int* __restrict__ degB,
              const int* __restrict__ bktB,
              unsigned short* __restrict__ Acat, int nDst) {
    int node = blockIdx.x * 4 + (threadIdx.x >> 6);
    if (node >= nDst) return;
    int lane = threadIdx.x & 63;
    unsigned* outrow = (unsigned*)(Acat + (size_t)node * 256);
    {
        int s = offA[node], n = degA[node];
        float ax = 0.f, ay = 0.f;
        #pragma unroll 4
        for (int j = 0; j < n; ++j) {
            int sidx = bktA[s + j];
            unsigned v = ((const unsigned*)(hA + (size_t)sidx * DIM))[lane];
            ax += bflo(v); ay += bfhi(v);
        }
        float inv = 1.0f / fmaxf((float)n, 1.0f);
        outrow[lane] = pack2(ax * inv, ay * inv);
    }
    {
        int s = offB[node], n = degB[node];
        float ax = 0.f, ay = 0.f;
        #pragma unroll 4
        for (int j = 0; j < n; ++j) {
            int sidx = bktB[s + j];
            unsigned v = ((const unsigned*)(hB + (size_t)sidx * DIM))[lane];
            ax += bflo(v); ay += bfhi(v);
        }
        float inv = 1.0f / fmaxf((float)n, 1.0f);
        outrow[64 + lane] = pack2(ax * inv, ay * inv);
    }
}

// ---------------- MFMA GEMM [M,256]bf16 @ [256,128]bf16 + bias + LeakyReLU + LN ----------
#define GBM 128
__global__ __launch_bounds__(256)
void gemm_ln_k(const unsigned short* __restrict__ A,   // [Mpad][256] bf16
               const unsigned short* __restrict__ Wp,  // packed frags, 64 KB
               const float* __restrict__ bias,
               const float* __restrict__ lns, const float* __restrict__ lnb,
               unsigned short* __restrict__ outh,      // bf16 table (layer 1) or null
               float* __restrict__ outf,               // f32 final (layer 2) or null
               int M) {
    __shared__ unsigned short Ws[32768];  // 64 KB
    int tid = threadIdx.x;
    {
        const uint4* s = (const uint4*)Wp;
        uint4* d = (uint4*)Ws;
        #pragma unroll
        for (int i = tid; i < 4096; i += 256) d[i] = s[i];
    }
    __syncthreads();

    int wave = tid >> 6, lane = tid & 63;
    int col0 = lane & 15;
    int kq = lane >> 4;
    int m_base = blockIdx.x * GBM + wave * 32;

    f32x4 acc[2][8];
    #pragma unroll
    for (int mt = 0; mt < 2; ++mt)
        #pragma unroll
        for (int t = 0; t < 8; ++t) acc[mt][t] = (f32x4){0.f, 0.f, 0.f, 0.f};

    const unsigned short* Ar0 = A + (size_t)(m_base + col0) * 256 + kq * 8;
    const unsigned short* Ar1 = Ar0 + 16 * 256;
    #pragma unroll
    for (int c = 0; c < 8; ++c) {
        bf16x8 a0 = *(const bf16x8*)(Ar0 + c * 32);
        bf16x8 a1 = *(const bf16x8*)(Ar1 + c * 32);
        #pragma unroll
        for (int t = 0; t < 8; ++t) {
            bf16x8 b = *(const bf16x8*)(Ws + ((t * 8 + c) * 64 + lane) * 8);
            acc[0][t] = __builtin_amdgcn_mfma_f32_16x16x32_bf16(a0, b, acc[0][t], 0, 0, 0);
            acc[1][t] = __builtin_amdgcn_mfma_f32_16x16x32_bf16(a1, b, acc[1][t], 0, 0, 0);
        }
    }

    float bias_r[8], s_r[8], b_r[8];
    #pragma unroll
    for (int t = 0; t < 8; ++t) {
        int col = t * 16 + col0;
        bias_r[t] = bias[col]; s_r[t] = lns[col]; b_r[t] = lnb[col];
    }
    #pragma unroll
    for (int mt = 0; mt < 2; ++mt) {
        #pragma unroll
        for (int r = 0; r < 4; ++r) {
            int row = m_base + mt * 16 + kq * 4 + r;
            float v[8]; float sum = 0.f, sq = 0.f;
            #pragma unroll
            for (int t = 0; t < 8; ++t) {
                float x = acc[mt][t][r] + bias_r[t];
                x = (x >= 0.f) ? x : SLOPE * x;
                v[t] = x; sum += x; sq += x * x;
            }
            #pragma unroll
            for (int ofs = 1; ofs <= 8; ofs <<= 1) {
                sum += __shfl_xor(sum, ofs);
                sq  += __shfl_xor(sq, ofs);
            }
            float mu = sum * (1.0f / 128.0f);
            float var = sq * (1.0f / 128.0f) - mu * mu;
            float rstd = rsqrtf(var + LN_EPS);
            if (row < M) {
                if (outh) {
                    #pragma unroll
                    for (int t = 0; t < 8; ++t)
                        outh[(size_t)row * 128 + t * 16 + col0] =
                            f2bf((v[t] - mu) * rstd * s_r[t] + b_r[t]);
                } else {
                    #pragma unroll
                    for (int t = 0; t < 8; ++t)
                        outf[(size_t)row * 128 + t * 16 + col0] =
                            (v[t] - mu) * rstd * s_r[t] + b_r[t];
                }
            }
        }
    }
}

extern "C" void kernel_launch(void* const* d_in, const int* in_sizes, int n_in,
                              void* d_out, int out_size, void* d_ws, size_t ws_size,
                              hipStream_t stream) {
    const float* h_cell = (const float*)d_in[0];
    const float* h_gene = (const float*)d_in[1];
    const int* src_cg = (const int*)d_in[2];
    const int* dst_cg = (const int*)d_in[3];
    const int* src_gc = (const int*)d_in[4];
    const int* dst_gc = (const int*)d_in[5];
    const int* src_cc = (const int*)d_in[6];
    const int* dst_cc = (const int*)d_in[7];
    const int* src_gg = (const int*)d_in[8];
    const int* dst_gg = (const int*)d_in[9];
    const float* W_cg = (const float*)d_in[10];
    const float* W_gc = (const float*)d_in[11];
    const float* W_cc = (const float*)d_in[12];
    const float* W_gg = (const float*)d_in[13];
    const float* b_cell = (const float*)d_in[14];
    const float* b_gene = (const float*)d_in[15];
    const float* ln_s_cell = (const float*)d_in[16];
    const float* ln_b_cell = (const float*)d_in[17];
    const float* ln_s_gene = (const float*)d_in[18];
    const float* ln_b_gene = (const float*)d_in[19];
    float* out = (float*)d_out;

    const int MPC = ((NCELL + GBM - 1) / GBM) * GBM;
    const int MPG = ((NGENE + GBM - 1) / GBM) * GBM;
    const int NB_C = (NCELL + 255) / 256;   // 391 bins (shift 8)
    const int NB_G = (NGENE + 15) / 16;     // 500 bins (shift 4)

    char* wsb = (char*)d_ws;
    size_t off = 0;
    auto alloc = [&](size_t bytes) -> char* {
        char* p = wsb + off;
        off = (off + bytes + 255) & ~(size_t)255;
        return p;
    };
    unsigned short* Acat_c = (unsigned short*)alloc((size_t)MPC * 256 * 2);
    unsigned short* Acat_g = (unsigned short*)alloc((size_t)MPG * 256 * 2);
    unsigned short* hcb0 = (unsigned short*)alloc((size_t)NCELL * DIM * 2);
    unsigned short* hgb0 = (unsigned short*)alloc((size_t)NGENE * DIM * 2);
    unsigned short* hcb1 = (unsigned short*)alloc((size_t)NCELL * DIM * 2);
    unsigned short* hgb1 = (unsigned short*)alloc((size_t)NGENE * DIM * 2);
    unsigned short* Wp_cell = (unsigned short*)alloc(65536);
    unsigned short* Wp_gene = (unsigned short*)alloc(65536);
    int ndeg = 2 * NCELL + 2 * NGENE;
    int* degs = (int*)alloc((size_t)ndeg * 4);
    int* deg_gc = degs;
    int* deg_cc = degs + NCELL;
    int* deg_cg = degs + 2 * NCELL;
    int* deg_gg = degs + 2 * NCELL + NGENE;
    int* offs = (int*)alloc((size_t)ndeg * 4);
    int* off_gc = offs;
    int* off_cc = offs + NCELL;
    int* off_cg = offs + 2 * NCELL;
    int* off_gg = offs + 2 * NCELL + NGENE;
    int* bkt_gc = (int*)alloc((size_t)NE_GC * 4);
    int* bkt_cc = (int*)alloc((size_t)NE_CC * 4);
    int* bkt_cg = (int*)alloc((size_t)NE_CG * 4);
    int* bkt_gg = (int*)alloc((size_t)NE_GG * 4);
    unsigned* stg = (unsigned*)alloc((size_t)NE_GC * 4);   // shared staging (max E)
    int* binmem = (int*)alloc(4 * 2048 * 4);               // 4 relations x {cnt,off,cur}

    // ---- input conversion + weight packing ----
    conv_bf16_k<<<(NCELL * DIM / 2 + 255) / 256, 256, 0, stream>>>(h_cell, hcb0, NCELL * DIM / 2);
    conv_bf16_k<<<(NGENE * DIM / 2 + 255) / 256, 256, 0, stream>>>(h_gene, hgb0, NGENE * DIM / 2);
    pack_w_k<<<64, 64, 0, stream>>>(W_gc, W_cc, Wp_cell);
    pack_w_k<<<64, 64, 0, stream>>>(W_cg, W_gg, Wp_gene);

    // ---- binned CSR build (sequential per relation; staging buffer reused) ----
    hipMemsetAsync(binmem, 0, 4 * 2048 * 4, stream);
    struct Rel { const int* src; const int* dst; int n; int shift; int nbins; int N;
                 int* deg; int* offg; int* bkt; int* bm; };
    Rel rels[4] = {
        { src_gc, dst_gc, NE_GC, 8, NB_C, NCELL, deg_gc, off_gc, bkt_gc, binmem + 0 * 2048 },
        { src_cc, dst_cc, NE_CC, 8, NB_C, NCELL, deg_cc, off_cc, bkt_cc, binmem + 1 * 2048 },
        { src_cg, dst_cg, NE_CG, 4, NB_G, NGENE, deg_cg, off_cg, bkt_cg, binmem + 2 * 2048 },
        { src_gg, dst_gg, NE_GG, 4, NB_G, NGENE, deg_gg, off_gg, bkt_gg, binmem + 3 * 2048 },
    };
    for (int r = 0; r < 4; ++r) {
        Rel& R = rels[r];
        int* bcnt = R.bm;
        int* boff = R.bm + 512;
        int* bcur = R.bm + 1025;
        int nblk = (R.n + 4095) / 4096;
        bin_count_k<<<nblk, 256, 0, stream>>>(R.dst, R.n, R.shift, bcnt);
        bin_scan_k<<<1, 512, 0, stream>>>(bcnt, boff, bcur, R.nbins);
        bin_fill_k<<<nblk, 256, 0, stream>>>(R.src, R.dst, R.n, R.shift, bcur, stg);
        bin_csr_k<<<R.nbins, 256, 0, stream>>>(stg, boff, R.shift, R.N, R.deg, R.offg, R.bkt);
    }

    // ---- two shared layers ----
    const unsigned short* hc = hcb0;
    const unsigned short* hg = hgb0;
    for (int layer = 0; layer < 2; ++layer) {
        int final_ = (layer == 1);
        gather_k<<<(NCELL + 3) / 4, 256, 0, stream>>>(hg, off_gc, deg_gc, bkt_gc,
                                                      hc, off_cc, deg_cc, bkt_cc,
                                                      Acat_c, NCELL);
        gather_k<<<(NGENE + 3) / 4, 256, 0, stream>>>(hc, off_cg, deg_cg, bkt_cg,
                                                      hg, off_gg, deg_gg, bkt_gg,
                                                      Acat_g, NGENE);
        gemm_ln_k<<<MPC / GBM, 256, 0, stream>>>(Acat_c, Wp_cell, b_cell, ln_s_cell, ln_b_cell,
                                                 final_ ? nullptr : hcb1,
                                                 final_ ? out : nullptr, NCELL);
        gemm_ln_k<<<MPG / GBM, 256, 0, stream>>>(Acat_g, Wp_gene, b_gene, ln_s_gene, ln_b_gene,
                                                 final_ ? nullptr : hgb1,
                                                 final_ ? out + (size_t)NCELL * DIM : nullptr, NGENE);
        hc = hcb1;
        hg = hgb1;
    }
}

// Round 4
// 600.636 us; speedup vs baseline: 2.3741x; 1.2727x over previous
//
#include <hip/hip_runtime.h>
#include <hip/hip_bf16.h>

#define NCELL 100000
#define NGENE 8000
#define DIM   128
#define NE_CG 1500000
#define NE_GC 1500000
#define NE_CC 1000000
#define NE_GG 200000
#define SLOPE 0.05f
#define LN_EPS 1e-5f

typedef __attribute__((ext_vector_type(8))) short bf16x8;
typedef __attribute__((ext_vector_type(4))) float f32x4;

__device__ __forceinline__ float bflo(unsigned v) { return __uint_as_float(v << 16); }
__device__ __forceinline__ float bfhi(unsigned v) { return __uint_as_float(v & 0xffff0000u); }
__device__ __forceinline__ unsigned short f2bf(float x) {
    union { float f; unsigned u; } a; a.f = x;
    unsigned r = a.u + 0x7fffu + ((a.u >> 16) & 1u);   // round-to-nearest-even
    return (unsigned short)(r >> 16);
}
__device__ __forceinline__ unsigned pack2(float x, float y) {
    return (unsigned)f2bf(x) | ((unsigned)f2bf(y) << 16);
}

// ---------------- fused f32 -> bf16 conversion (cell then gene) ----------------
__global__ __launch_bounds__(256)
void conv2_k(const float* __restrict__ inc, unsigned short* __restrict__ outc,
             const float* __restrict__ ing, unsigned short* __restrict__ outg,
             int cellBlocks, int n2c, int n2g) {
    const float* in; unsigned short* out; int i, n2;
    if ((int)blockIdx.x < cellBlocks) {
        in = inc; out = outc; n2 = n2c; i = blockIdx.x * 256 + threadIdx.x;
    } else {
        in = ing; out = outg; n2 = n2g; i = (blockIdx.x - cellBlocks) * 256 + threadIdx.x;
    }
    if (i < n2) {
        float2 v = ((const float2*)in)[i];
        ((unsigned*)out)[i] = pack2(v.x, v.y);
    }
}

// ---------------- fused weight pack: [W1;W2] -> MFMA B-frag layout ----------------
__global__ void pack2_w_k(const float* __restrict__ WAc, const float* __restrict__ WBc,
                          unsigned short* __restrict__ Wpc,
                          const float* __restrict__ WAg, const float* __restrict__ WBg,
                          unsigned short* __restrict__ Wpg) {
    int bb = blockIdx.x;
    const float *WA, *WB; unsigned short* Wp;
    if (bb < 64) { WA = WAc; WB = WBc; Wp = Wpc; }
    else { bb -= 64; WA = WAg; WB = WBg; Wp = Wpg; }
    int lane = threadIdx.x;   // 64
    int t = bb >> 3, c = bb & 7;
    int n = t * 16 + (lane & 15);
    int k0 = c * 32 + (lane >> 4) * 8;
    #pragma unroll
    for (int j = 0; j < 8; ++j) {
        int k = k0 + j;
        float x = (k < 128) ? WA[k * 128 + n] : WB[(k - 128) * 128 + n];
        Wp[((size_t)(bb * 64 + lane)) * 8 + j] = f2bf(x);
    }
}

// ================= binned CSR build (4 relations fused per phase) =================
struct RelP {
    const int* src; const int* dst; int n; int shift;
    int nbins; int N;
    int* deg; int* offg; int* bkt;
    int* bcnt; int* boff; int* bcur; unsigned* stg;
    int cblk0;   // first block id in count/fill grid
    int sblk0;   // first block id in csr grid
};

__global__ __launch_bounds__(256)
void bin_count4_k(RelP r0, RelP r1, RelP r2, RelP r3) {
    int b = blockIdx.x;
    RelP R = (b >= r3.cblk0) ? r3 : (b >= r2.cblk0) ? r2 : (b >= r1.cblk0) ? r1 : r0;
    int lb = b - R.cblk0;
    __shared__ int cnt[512];
    int tid = threadIdx.x;
    cnt[tid] = 0; cnt[tid + 256] = 0;
    __syncthreads();
    int base = lb * 4096;
    #pragma unroll
    for (int it = 0; it < 16; ++it) {
        int i = base + it * 256 + tid;
        if (i < R.n) atomicAdd(&cnt[R.dst[i] >> R.shift], 1);
    }
    __syncthreads();
    if (cnt[tid])       atomicAdd(&R.bcnt[tid], cnt[tid]);
    if (cnt[tid + 256]) atomicAdd(&R.bcnt[tid + 256], cnt[tid + 256]);
}

__global__ __launch_bounds__(512)
void bin_scan4_k(RelP r0, RelP r1, RelP r2, RelP r3) {
    RelP R = (blockIdx.x == 0) ? r0 : (blockIdx.x == 1) ? r1 : (blockIdx.x == 2) ? r2 : r3;
    __shared__ int sm[512];
    int tid = threadIdx.x;
    int x = (tid < R.nbins) ? R.bcnt[tid] : 0;
    sm[tid] = x;
    __syncthreads();
    for (int ofs = 1; ofs < 512; ofs <<= 1) {
        int t = (tid >= ofs) ? sm[tid - ofs] : 0;
        __syncthreads();
        sm[tid] += t;
        __syncthreads();
    }
    int excl = sm[tid] - x;
    if (tid < R.nbins) { R.boff[tid] = excl; R.bcur[tid] = excl; }
    if (tid == 511) R.boff[R.nbins] = sm[511];
}

__global__ __launch_bounds__(256)
void bin_fill4_k(RelP r0, RelP r1, RelP r2, RelP r3) {
    int b = blockIdx.x;
    RelP R = (b >= r3.cblk0) ? r3 : (b >= r2.cblk0) ? r2 : (b >= r1.cblk0) ? r1 : r0;
    int lb = b - R.cblk0;
    __shared__ int cnt[512];
    __shared__ int basem[512];
    int tid = threadIdx.x;
    cnt[tid] = 0; cnt[tid + 256] = 0;
    __syncthreads();
    int base = lb * 4096;
    int bins[16]; int ranks[16]; unsigned pk[16];
    #pragma unroll
    for (int it = 0; it < 16; ++it) {
        int i = base + it * 256 + tid;
        bins[it] = -1;
        if (i < R.n) {
            int d = R.dst[i];
            int bn = d >> R.shift;
            int dl = d & ((1 << R.shift) - 1);
            bins[it] = bn;
            pk[it] = (unsigned)R.src[i] | ((unsigned)dl << 20);
            ranks[it] = atomicAdd(&cnt[bn], 1);
        }
    }
    __syncthreads();
    if (cnt[tid])       basem[tid]       = atomicAdd(&R.bcur[tid],       cnt[tid]);
    if (cnt[tid + 256]) basem[tid + 256] = atomicAdd(&R.bcur[tid + 256], cnt[tid + 256]);
    __syncthreads();
    #pragma unroll
    for (int it = 0; it < 16; ++it)
        if (bins[it] >= 0) R.stg[basem[bins[it]] + ranks[it]] = pk[it];
}

__global__ __launch_bounds__(256)
void bin_csr4_k(RelP r0, RelP r1, RelP r2, RelP r3) {
    int b = blockIdx.x;
    RelP R = (b >= r3.sblk0) ? r3 : (b >= r2.sblk0) ? r2 : (b >= r1.sblk0) ? r1 : r0;
    int lb = b - R.sblk0;
    int tid = threadIdx.x;
    int e0 = R.boff[lb], e1 = R.boff[lb + 1];
    __shared__ int degm[256];
    __shared__ int sc[256];
    __shared__ int cur[256];
    degm[tid] = 0;
    __syncthreads();
    for (int i = e0 + tid; i < e1; i += 256)
        atomicAdd(&degm[(R.stg[i] >> 20) & 255], 1);
    __syncthreads();
    int x = degm[tid];
    sc[tid] = x;
    __syncthreads();
    for (int ofs = 1; ofs < 256; ofs <<= 1) {
        int t = (tid >= ofs) ? sc[tid - ofs] : 0;
        __syncthreads();
        sc[tid] += t;
        __syncthreads();
    }
    int excl = sc[tid] - x;
    cur[tid] = excl;
    int node = (lb << R.shift) + tid;
    if (tid < (1 << R.shift) && node < R.N) { R.deg[node] = x; R.offg[node] = e0 + excl; }
    __syncthreads();
    for (int i = e0 + tid; i < e1; i += 256) {
        unsigned p = R.stg[i];
        int dl = (p >> 20) & 255;
        int r = atomicAdd(&cur[dl], 1);
        R.bkt[e0 + r] = (int)(p & 0xFFFFFu);
    }
}

// ---------------- fused vectorized gather: 16 lanes/row, 16 B/lane, 4 edges/load ------
__global__ __launch_bounds__(256)
void gather2_k(const unsigned short* __restrict__ hc, const unsigned short* __restrict__ hg,
               const int* __restrict__ off_gc, const int* __restrict__ deg_gc, const int* __restrict__ bkt_gc,
               const int* __restrict__ off_cc, const int* __restrict__ deg_cc, const int* __restrict__ bkt_cc,
               const int* __restrict__ off_cg, const int* __restrict__ deg_cg, const int* __restrict__ bkt_cg,
               const int* __restrict__ off_gg, const int* __restrict__ deg_gg, const int* __restrict__ bkt_gg,
               unsigned short* __restrict__ Acat_c, unsigned short* __restrict__ Acat_g,
               int cellBlocks) {
    int wave = threadIdx.x >> 6, lane = threadIdx.x & 63;
    int g = lane >> 4, c = lane & 15;
    const unsigned short *hA, *hB;
    const int *offA, *degA, *bktA, *offB, *degB, *bktB;
    unsigned short* Aout; int node, N;
    if ((int)blockIdx.x < cellBlocks) {
        node = blockIdx.x * 4 + wave; N = NCELL;
        hA = hg; offA = off_gc; degA = deg_gc; bktA = bkt_gc;
        hB = hc; offB = off_cc; degB = deg_cc; bktB = bkt_cc;
        Aout = Acat_c;
    } else {
        node = (blockIdx.x - cellBlocks) * 4 + wave; N = NGENE;
        hA = hc; offA = off_cg; degA = deg_cg; bktA = bkt_cg;
        hB = hg; offB = off_gg; degB = deg_gg; bktB = bkt_gg;
        Aout = Acat_g;
    }
    if (node >= N) return;

    float aA[8] = {0.f, 0.f, 0.f, 0.f, 0.f, 0.f, 0.f, 0.f};
    float aB[8] = {0.f, 0.f, 0.f, 0.f, 0.f, 0.f, 0.f, 0.f};
    int nA = degA[node], sA = offA[node];
    int nB = degB[node], sB = offB[node];

    #pragma unroll 2
    for (int j0 = 0; j0 < nA; j0 += 4) {
        int j = j0 + g;
        int jc = (j < nA) ? j : nA - 1;
        int sidx = bktA[sA + jc];
        uint4 v = *(const uint4*)(hA + (size_t)sidx * DIM + c * 8);
        if (j < nA) {
            aA[0] += bflo(v.x); aA[1] += bfhi(v.x);
            aA[2] += bflo(v.y); aA[3] += bfhi(v.y);
            aA[4] += bflo(v.z); aA[5] += bfhi(v.z);
            aA[6] += bflo(v.w); aA[7] += bfhi(v.w);
        }
    }
    #pragma unroll 2
    for (int j0 = 0; j0 < nB; j0 += 4) {
        int j = j0 + g;
        int jc = (j < nB) ? j : nB - 1;
        int sidx = bktB[sB + jc];
        uint4 v = *(const uint4*)(hB + (size_t)sidx * DIM + c * 8);
        if (j < nB) {
            aB[0] += bflo(v.x); aB[1] += bfhi(v.x);
            aB[2] += bflo(v.y); aB[3] += bfhi(v.y);
            aB[4] += bflo(v.z); aB[5] += bfhi(v.z);
            aB[6] += bflo(v.w); aB[7] += bfhi(v.w);
        }
    }
    #pragma unroll
    for (int i = 0; i < 8; ++i) {
        aA[i] += __shfl_xor(aA[i], 16); aA[i] += __shfl_xor(aA[i], 32);
        aB[i] += __shfl_xor(aB[i], 16); aB[i] += __shfl_xor(aB[i], 32);
    }
    float invA = 1.0f / fmaxf((float)nA, 1.0f);
    float invB = 1.0f / fmaxf((float)nB, 1.0f);
    uint4* outrow = (uint4*)(Aout + (size_t)node * 256);
    if (g == 0) {
        outrow[c] = make_uint4(pack2(aA[0] * invA, aA[1] * invA), pack2(aA[2] * invA, aA[3] * invA),
                               pack2(aA[4] * invA, aA[5] * invA), pack2(aA[6] * invA, aA[7] * invA));
    } else if (g == 1) {
        outrow[16 + c] = make_uint4(pack2(aB[0] * invB, aB[1] * invB), pack2(aB[2] * invB, aB[3] * invB),
                                    pack2(aB[4] * invB, aB[5] * invB), pack2(aB[6] * invB, aB[7] * invB));
    }
}

// ---------------- fused MFMA GEMM + bias + LeakyReLU + LN (cell & gene) ----------------
#define GBM 128
__global__ __launch_bounds__(256)
void gemm2_ln_k(const unsigned short* __restrict__ Acat_c, const unsigned short* __restrict__ Acat_g,
                const unsigned short* __restrict__ Wp_c, const unsigned short* __restrict__ Wp_g,
                const float* __restrict__ bias_c, const float* __restrict__ bias_g,
                const float* __restrict__ ls_c, const float* __restrict__ lb_c,
                const float* __restrict__ ls_g, const float* __restrict__ lb_g,
                unsigned short* __restrict__ outh_c, unsigned short* __restrict__ outh_g,
                float* __restrict__ outf_c, float* __restrict__ outf_g,
                int cellBlocks) {
    const unsigned short *A, *Wp; const float *bias, *lns, *lnb;
    unsigned short* outh; float* outf; int M, mb;
    if ((int)blockIdx.x < cellBlocks) {
        A = Acat_c; Wp = Wp_c; bias = bias_c; lns = ls_c; lnb = lb_c;
        outh = outh_c; outf = outf_c; M = NCELL; mb = blockIdx.x;
    } else {
        A = Acat_g; Wp = Wp_g; bias = bias_g; lns = ls_g; lnb = lb_g;
        outh = outh_g; outf = outf_g; M = NGENE; mb = blockIdx.x - cellBlocks;
    }
    __shared__ unsigned short Ws[32768];  // 64 KB
    int tid = threadIdx.x;
    {
        const uint4* s = (const uint4*)Wp;
        uint4* d = (uint4*)Ws;
        #pragma unroll
        for (int i = tid; i < 4096; i += 256) d[i] = s[i];
    }
    __syncthreads();

    int wave = tid >> 6, lane = tid & 63;
    int col0 = lane & 15;
    int kq = lane >> 4;
    int m_base = mb * GBM + wave * 32;

    f32x4 acc[2][8];
    #pragma unroll
    for (int mt = 0; mt < 2; ++mt)
        #pragma unroll
        for (int t = 0; t < 8; ++t) acc[mt][t] = (f32x4){0.f, 0.f, 0.f, 0.f};

    const unsigned short* Ar0 = A + (size_t)(m_base + col0) * 256 + kq * 8;
    const unsigned short* Ar1 = Ar0 + 16 * 256;
    #pragma unroll
    for (int c = 0; c < 8; ++c) {
        bf16x8 a0 = *(const bf16x8*)(Ar0 + c * 32);
        bf16x8 a1 = *(const bf16x8*)(Ar1 + c * 32);
        #pragma unroll
        for (int t = 0; t < 8; ++t) {
            bf16x8 b = *(const bf16x8*)(Ws + ((t * 8 + c) * 64 + lane) * 8);
            acc[0][t] = __builtin_amdgcn_mfma_f32_16x16x32_bf16(a0, b, acc[0][t], 0, 0, 0);
            acc[1][t] = __builtin_amdgcn_mfma_f32_16x16x32_bf16(a1, b, acc[1][t], 0, 0, 0);
        }
    }

    float bias_r[8], s_r[8], b_r[8];
    #pragma unroll
    for (int t = 0; t < 8; ++t) {
        int col = t * 16 + col0;
        bias_r[t] = bias[col]; s_r[t] = lns[col]; b_r[t] = lnb[col];
    }
    #pragma unroll
    for (int mt = 0; mt < 2; ++mt) {
        #pragma unroll
        for (int r = 0; r < 4; ++r) {
            int row = m_base + mt * 16 + kq * 4 + r;
            float v[8]; float sum = 0.f, sq = 0.f;
            #pragma unroll
            for (int t = 0; t < 8; ++t) {
                float x = acc[mt][t][r] + bias_r[t];
                x = (x >= 0.f) ? x : SLOPE * x;
                v[t] = x; sum += x; sq += x * x;
            }
            #pragma unroll
            for (int ofs = 1; ofs <= 8; ofs <<= 1) {
                sum += __shfl_xor(sum, ofs);
                sq  += __shfl_xor(sq, ofs);
            }
            float mu = sum * (1.0f / 128.0f);
            float var = sq * (1.0f / 128.0f) - mu * mu;
            float rstd = rsqrtf(var + LN_EPS);
            if (row < M) {
                if (outh) {
                    #pragma unroll
                    for (int t = 0; t < 8; ++t)
                        outh[(size_t)row * 128 + t * 16 + col0] =
                            f2bf((v[t] - mu) * rstd * s_r[t] + b_r[t]);
                } else {
                    #pragma unroll
                    for (int t = 0; t < 8; ++t)
                        outf[(size_t)row * 128 + t * 16 + col0] =
                            (v[t] - mu) * rstd * s_r[t] + b_r[t];
                }
            }
        }
    }
}

extern "C" void kernel_launch(void* const* d_in, const int* in_sizes, int n_in,
                              void* d_out, int out_size, void* d_ws, size_t ws_size,
                              hipStream_t stream) {
    const float* h_cell = (const float*)d_in[0];
    const float* h_gene = (const float*)d_in[1];
    const int* src_cg = (const int*)d_in[2];
    const int* dst_cg = (const int*)d_in[3];
    const int* src_gc = (const int*)d_in[4];
    const int* dst_gc = (const int*)d_in[5];
    const int* src_cc = (const int*)d_in[6];
    const int* dst_cc = (const int*)d_in[7];
    const int* src_gg = (const int*)d_in[8];
    const int* dst_gg = (const int*)d_in[9];
    const float* W_cg = (const float*)d_in[10];
    const float* W_gc = (const float*)d_in[11];
    const float* W_cc = (const float*)d_in[12];
    const float* W_gg = (const float*)d_in[13];
    const float* b_cell = (const float*)d_in[14];
    const float* b_gene = (const float*)d_in[15];
    const float* ln_s_cell = (const float*)d_in[16];
    const float* ln_b_cell = (const float*)d_in[17];
    const float* ln_s_gene = (const float*)d_in[18];
    const float* ln_b_gene = (const float*)d_in[19];
    float* out = (float*)d_out;

    const int MPC = ((NCELL + GBM - 1) / GBM) * GBM;
    const int MPG = ((NGENE + GBM - 1) / GBM) * GBM;
    const int NB_C = (NCELL + 255) / 256;   // 391 bins (shift 8)
    const int NB_G = (NGENE + 15) / 16;     // 500 bins (shift 4)

    char* wsb = (char*)d_ws;
    size_t off = 0;
    auto alloc = [&](size_t bytes) -> char* {
        char* p = wsb + off;
        off = (off + bytes + 255) & ~(size_t)255;
        return p;
    };
    unsigned short* Acat_c = (unsigned short*)alloc((size_t)MPC * 256 * 2);
    unsigned short* Acat_g = (unsigned short*)alloc((size_t)MPG * 256 * 2);
    unsigned short* hcb0 = (unsigned short*)alloc((size_t)NCELL * DIM * 2);
    unsigned short* hgb0 = (unsigned short*)alloc((size_t)NGENE * DIM * 2);
    unsigned short* hcb1 = (unsigned short*)alloc((size_t)NCELL * DIM * 2);
    unsigned short* hgb1 = (unsigned short*)alloc((size_t)NGENE * DIM * 2);
    unsigned short* Wp_cell = (unsigned short*)alloc(65536);
    unsigned short* Wp_gene = (unsigned short*)alloc(65536);
    int ndeg = 2 * NCELL + 2 * NGENE;
    int* degs = (int*)alloc((size_t)ndeg * 4);
    int* deg_gc = degs;
    int* deg_cc = degs + NCELL;
    int* deg_cg = degs + 2 * NCELL;
    int* deg_gg = degs + 2 * NCELL + NGENE;
    int* offs = (int*)alloc((size_t)ndeg * 4);
    int* off_gc = offs;
    int* off_cc = offs + NCELL;
    int* off_cg = offs + 2 * NCELL;
    int* off_gg = offs + 2 * NCELL + NGENE;
    int* bkt_gc = (int*)alloc((size_t)NE_GC * 4);
    int* bkt_cc = (int*)alloc((size_t)NE_CC * 4);
    int* bkt_cg = (int*)alloc((size_t)NE_CG * 4);
    int* bkt_gg = (int*)alloc((size_t)NE_GG * 4);
    unsigned* stg_gc = (unsigned*)alloc((size_t)NE_GC * 4);
    unsigned* stg_cc = (unsigned*)alloc((size_t)NE_CC * 4);
    unsigned* stg_cg = (unsigned*)alloc((size_t)NE_CG * 4);
    unsigned* stg_gg = (unsigned*)alloc((size_t)NE_GG * 4);
    int* binmem = (int*)alloc(4 * 2048 * 4);

    // ---- input conversion + weight packing (fused) ----
    const int n2c = NCELL * DIM / 2, n2g = NGENE * DIM / 2;
    const int convCB = (n2c + 255) / 256;
    const int convGB = (n2g + 255) / 256;
    conv2_k<<<convCB + convGB, 256, 0, stream>>>(h_cell, hcb0, h_gene, hgb0, convCB, n2c, n2g);
    pack2_w_k<<<128, 64, 0, stream>>>(W_gc, W_cc, Wp_cell, W_cg, W_gg, Wp_gene);

    // ---- binned CSR build, 4 relations per phase ----
    hipMemsetAsync(binmem, 0, 4 * 2048 * 4, stream);
    const int nbk_gc = (NE_GC + 4095) / 4096;   // 367
    const int nbk_cc = (NE_CC + 4095) / 4096;   // 245
    const int nbk_cg = (NE_CG + 4095) / 4096;   // 367
    const int nbk_gg = (NE_GG + 4095) / 4096;   // 49
    auto mkrel = [&](const int* s, const int* d, int n, int shift, int nbins, int N,
                     int* deg, int* offg, int* bkt, int* bm, unsigned* stg,
                     int cblk0, int sblk0) {
        RelP r;
        r.src = s; r.dst = d; r.n = n; r.shift = shift; r.nbins = nbins; r.N = N;
        r.deg = deg; r.offg = offg; r.bkt = bkt;
        r.bcnt = bm; r.boff = bm + 512; r.bcur = bm + 1056; r.stg = stg;
        r.cblk0 = cblk0; r.sblk0 = sblk0;
        return r;
    };
    RelP r0 = mkrel(src_gc, dst_gc, NE_GC, 8, NB_C, NCELL, deg_gc, off_gc, bkt_gc,
                    binmem + 0 * 2048, stg_gc, 0, 0);
    RelP r1 = mkrel(src_cc, dst_cc, NE_CC, 8, NB_C, NCELL, deg_cc, off_cc, bkt_cc,
                    binmem + 1 * 2048, stg_cc, nbk_gc, NB_C);
    RelP r2 = mkrel(src_cg, dst_cg, NE_CG, 4, NB_G, NGENE, deg_cg, off_cg, bkt_cg,
                    binmem + 2 * 2048, stg_cg, nbk_gc + nbk_cc, 2 * NB_C);
    RelP r3 = mkrel(src_gg, dst_gg, NE_GG, 4, NB_G, NGENE, deg_gg, off_gg, bkt_gg,
                    binmem + 3 * 2048, stg_gg, nbk_gc + nbk_cc + nbk_cg, 2 * NB_C + NB_G);
    const int cntBlocks = nbk_gc + nbk_cc + nbk_cg + nbk_gg;
    const int csrBlocks = 2 * NB_C + 2 * NB_G;
    bin_count4_k<<<cntBlocks, 256, 0, stream>>>(r0, r1, r2, r3);
    bin_scan4_k<<<4, 512, 0, stream>>>(r0, r1, r2, r3);
    bin_fill4_k<<<cntBlocks, 256, 0, stream>>>(r0, r1, r2, r3);
    bin_csr4_k<<<csrBlocks, 256, 0, stream>>>(r0, r1, r2, r3);

    // ---- two shared layers ----
    const int gatherCB = NCELL / 4;           // 25000
    const int gatherGB = (NGENE + 3) / 4;     // 2000
    const int gemmCB = MPC / GBM;             // 782
    const int gemmGB = MPG / GBM;             // 63
    const unsigned short* hc = hcb0;
    const unsigned short* hg = hgb0;
    for (int layer = 0; layer < 2; ++layer) {
        int final_ = (layer == 1);
        gather2_k<<<gatherCB + gatherGB, 256, 0, stream>>>(
            hc, hg,
            off_gc, deg_gc, bkt_gc, off_cc, deg_cc, bkt_cc,
            off_cg, deg_cg, bkt_cg, off_gg, deg_gg, bkt_gg,
            Acat_c, Acat_g, gatherCB);
        gemm2_ln_k<<<gemmCB + gemmGB, 256, 0, stream>>>(
            Acat_c, Acat_g, Wp_cell, Wp_gene, b_cell, b_gene,
            ln_s_cell, ln_b_cell, ln_s_gene, ln_b_gene,
            final_ ? nullptr : hcb1, final_ ? nullptr : hgb1,
            final_ ? out : nullptr, final_ ? out + (size_t)NCELL * DIM : nullptr,
            gemmCB);
        hc = hcb1;
        hg = hgb1;
    }
}

// Round 5
// 580.756 us; speedup vs baseline: 2.4554x; 1.0342x over previous
//
#include <hip/hip_runtime.h>
#include <hip/hip_bf16.h>

#define NCELL 100000
#define NGENE 8000
#define DIM   128
#define NE_CG 1500000
#define NE_GC 1500000
#define NE_CC 1000000
#define NE_GG 200000
#define SLOPE 0.05f
#define LN_EPS 1e-5f

typedef __attribute__((ext_vector_type(8))) short bf16x8;
typedef __attribute__((ext_vector_type(4))) float f32x4;

__device__ __forceinline__ float bflo(unsigned v) { return __uint_as_float(v << 16); }
__device__ __forceinline__ float bfhi(unsigned v) { return __uint_as_float(v & 0xffff0000u); }
__device__ __forceinline__ unsigned short f2bf(float x) {
    union { float f; unsigned u; } a; a.f = x;
    unsigned r = a.u + 0x7fffu + ((a.u >> 16) & 1u);   // round-to-nearest-even
    return (unsigned short)(r >> 16);
}
__device__ __forceinline__ unsigned pack2(float x, float y) {
    return (unsigned)f2bf(x) | ((unsigned)f2bf(y) << 16);
}

// ---------------- fused f32 -> bf16 conversion (cell then gene) ----------------
__global__ __launch_bounds__(256)
void conv2_k(const float* __restrict__ inc, unsigned short* __restrict__ outc,
             const float* __restrict__ ing, unsigned short* __restrict__ outg,
             int cellBlocks, int n2c, int n2g) {
    const float* in; unsigned short* out; int i, n2;
    if ((int)blockIdx.x < cellBlocks) {
        in = inc; out = outc; n2 = n2c; i = blockIdx.x * 256 + threadIdx.x;
    } else {
        in = ing; out = outg; n2 = n2g; i = (blockIdx.x - cellBlocks) * 256 + threadIdx.x;
    }
    if (i < n2) {
        float2 v = ((const float2*)in)[i];
        ((unsigned*)out)[i] = pack2(v.x, v.y);
    }
}

// ---------------- fused weight pack: [W1;W2] -> MFMA B-frag layout ----------------
__global__ void pack2_w_k(const float* __restrict__ WAc, const float* __restrict__ WBc,
                          unsigned short* __restrict__ Wpc,
                          const float* __restrict__ WAg, const float* __restrict__ WBg,
                          unsigned short* __restrict__ Wpg) {
    int bb = blockIdx.x;
    const float *WA, *WB; unsigned short* Wp;
    if (bb < 64) { WA = WAc; WB = WBc; Wp = Wpc; }
    else { bb -= 64; WA = WAg; WB = WBg; Wp = Wpg; }
    int lane = threadIdx.x;   // 64
    int t = bb >> 3, c = bb & 7;
    int n = t * 16 + (lane & 15);
    int k0 = c * 32 + (lane >> 4) * 8;
    #pragma unroll
    for (int j = 0; j < 8; ++j) {
        int k = k0 + j;
        float x = (k < 128) ? WA[k * 128 + n] : WB[(k - 128) * 128 + n];
        Wp[((size_t)(bb * 64 + lane)) * 8 + j] = f2bf(x);
    }
}

// ================= binned CSR build, fixed-capacity bins (no count/scan passes) ========
// bin = dst >> shift; staging slot = bin*cap + rank (rank via one reservation atomic).
// caps are mean + >8 sigma for Poisson bin sizes -> overflow probability ~1e-13.
struct RelP {
    const int* src; const int* dst; int n; int shift;
    int nbins; int N; int cap;
    int* deg; int* offg; int* bkt;
    int* bcur; unsigned* stg;
    int cblk0;   // first block id in fill grid
    int sblk0;   // first block id in csr grid
};

__global__ __launch_bounds__(256)
void bin_fill4_k(RelP r0, RelP r1, RelP r2, RelP r3) {
    int b = blockIdx.x;
    RelP R = (b >= r3.cblk0) ? r3 : (b >= r2.cblk0) ? r2 : (b >= r1.cblk0) ? r1 : r0;
    int lb = b - R.cblk0;
    __shared__ int cnt[512];
    __shared__ int basem[512];
    int tid = threadIdx.x;
    cnt[tid] = 0; cnt[tid + 256] = 0;
    __syncthreads();
    int base = lb * 4096;
    int bins[16]; int ranks[16]; unsigned pk[16];
    #pragma unroll
    for (int it = 0; it < 16; ++it) {
        int i = base + it * 256 + tid;
        bins[it] = -1;
        if (i < R.n) {
            int d = R.dst[i];
            int bn = d >> R.shift;
            int dl = d & ((1 << R.shift) - 1);
            bins[it] = bn;
            pk[it] = (unsigned)R.src[i] | ((unsigned)dl << 20);
            ranks[it] = atomicAdd(&cnt[bn], 1);
        }
    }
    __syncthreads();
    if (cnt[tid])       basem[tid]       = atomicAdd(&R.bcur[tid],       cnt[tid]);
    if (cnt[tid + 256]) basem[tid + 256] = atomicAdd(&R.bcur[tid + 256], cnt[tid + 256]);
    __syncthreads();
    #pragma unroll
    for (int it = 0; it < 16; ++it)
        if (bins[it] >= 0) {
            int r = basem[bins[it]] + ranks[it];
            if (r >= R.cap) r = R.cap - 1;           // paranoia clamp (stays in own bin)
            R.stg[(size_t)bins[it] * R.cap + r] = pk[it];
        }
}

__global__ __launch_bounds__(256)
void bin_csr4_k(RelP r0, RelP r1, RelP r2, RelP r3) {
    int b = blockIdx.x;
    RelP R = (b >= r3.sblk0) ? r3 : (b >= r2.sblk0) ? r2 : (b >= r1.sblk0) ? r1 : r0;
    int lb = b - R.sblk0;
    int tid = threadIdx.x;
    int ebase = lb * R.cap;
    int cnt = R.bcur[lb]; if (cnt > R.cap) cnt = R.cap;
    __shared__ int degm[256];
    __shared__ int sc[256];
    __shared__ int cur[256];
    degm[tid] = 0;
    __syncthreads();
    for (int i = tid; i < cnt; i += 256)
        atomicAdd(&degm[(R.stg[ebase + i] >> 20) & 255], 1);
    __syncthreads();
    int x = degm[tid];
    sc[tid] = x;
    __syncthreads();
    for (int ofs = 1; ofs < 256; ofs <<= 1) {
        int t = (tid >= ofs) ? sc[tid - ofs] : 0;
        __syncthreads();
        sc[tid] += t;
        __syncthreads();
    }
    int excl = sc[tid] - x;
    cur[tid] = excl;
    int node = (lb << R.shift) + tid;
    if (tid < (1 << R.shift) && node < R.N) { R.deg[node] = x; R.offg[node] = ebase + excl; }
    __syncthreads();
    for (int i = tid; i < cnt; i += 256) {
        unsigned p = R.stg[ebase + i];
        int dl = (p >> 20) & 255;
        int r = atomicAdd(&cur[dl], 1);
        R.bkt[ebase + r] = (int)(p & 0xFFFFFu);
    }
}

// ---------------- fused vectorized gather: merged-relation loop, deep unroll ----------
__global__ __launch_bounds__(256)
void gather2_k(const unsigned short* __restrict__ hc, const unsigned short* __restrict__ hg,
               const int* __restrict__ off_gc, const int* __restrict__ deg_gc, const int* __restrict__ bkt_gc,
               const int* __restrict__ off_cc, const int* __restrict__ deg_cc, const int* __restrict__ bkt_cc,
               const int* __restrict__ off_cg, const int* __restrict__ deg_cg, const int* __restrict__ bkt_cg,
               const int* __restrict__ off_gg, const int* __restrict__ deg_gg, const int* __restrict__ bkt_gg,
               unsigned short* __restrict__ Acat_c, unsigned short* __restrict__ Acat_g,
               int cellBlocks) {
    int wave = threadIdx.x >> 6, lane = threadIdx.x & 63;
    int g = lane >> 4, c = lane & 15;
    const unsigned short *hA, *hB;
    const int *offA, *degA, *bktA, *offB, *degB, *bktB;
    unsigned short* Aout; int node, N;
    if ((int)blockIdx.x < cellBlocks) {
        node = blockIdx.x * 4 + wave; N = NCELL;
        hA = hg; offA = off_gc; degA = deg_gc; bktA = bkt_gc;
        hB = hc; offB = off_cc; degB = deg_cc; bktB = bkt_cc;
        Aout = Acat_c;
    } else {
        node = (blockIdx.x - cellBlocks) * 4 + wave; N = NGENE;
        hA = hc; offA = off_cg; degA = deg_cg; bktA = bkt_cg;
        hB = hg; offB = off_gg; degB = deg_gg; bktB = bkt_gg;
        Aout = Acat_g;
    }
    if (node >= N) return;

    int nA = degA[node], sA = offA[node];
    int nB = degB[node], sB = offB[node];
    float aA[8] = {0.f, 0.f, 0.f, 0.f, 0.f, 0.f, 0.f, 0.f};
    float aB[8] = {0.f, 0.f, 0.f, 0.f, 0.f, 0.f, 0.f, 0.f};
    int mx = (nA > nB) ? nA : nB;

    #pragma unroll 4
    for (int j0 = 0; j0 < mx; j0 += 4) {
        int j = j0 + g;
        if (j < nA) {
            int sidx = bktA[sA + j];
            uint4 v = *(const uint4*)(hA + (size_t)sidx * DIM + c * 8);
            aA[0] += bflo(v.x); aA[1] += bfhi(v.x);
            aA[2] += bflo(v.y); aA[3] += bfhi(v.y);
            aA[4] += bflo(v.z); aA[5] += bfhi(v.z);
            aA[6] += bflo(v.w); aA[7] += bfhi(v.w);
        }
        if (j < nB) {
            int sidx = bktB[sB + j];
            uint4 v = *(const uint4*)(hB + (size_t)sidx * DIM + c * 8);
            aB[0] += bflo(v.x); aB[1] += bfhi(v.x);
            aB[2] += bflo(v.y); aB[3] += bfhi(v.y);
            aB[4] += bflo(v.z); aB[5] += bfhi(v.z);
            aB[6] += bflo(v.w); aB[7] += bfhi(v.w);
        }
    }
    #pragma unroll
    for (int i = 0; i < 8; ++i) {
        aA[i] += __shfl_xor(aA[i], 16); aA[i] += __shfl_xor(aA[i], 32);
        aB[i] += __shfl_xor(aB[i], 16); aB[i] += __shfl_xor(aB[i], 32);
    }
    float invA = 1.0f / fmaxf((float)nA, 1.0f);
    float invB = 1.0f / fmaxf((float)nB, 1.0f);
    uint4* outrow = (uint4*)(Aout + (size_t)node * 256);
    if (g == 0) {
        outrow[c] = make_uint4(pack2(aA[0] * invA, aA[1] * invA), pack2(aA[2] * invA, aA[3] * invA),
                               pack2(aA[4] * invA, aA[5] * invA), pack2(aA[6] * invA, aA[7] * invA));
    } else if (g == 1) {
        outrow[16 + c] = make_uint4(pack2(aB[0] * invB, aB[1] * invB), pack2(aB[2] * invB, aB[3] * invB),
                                    pack2(aB[4] * invB, aB[5] * invB), pack2(aB[6] * invB, aB[7] * invB));
    }
}

// ---------------- fused MFMA GEMM + bias + LeakyReLU + LN (cell & gene) ----------------
#define GBM 128
__global__ __launch_bounds__(256)
void gemm2_ln_k(const unsigned short* __restrict__ Acat_c, const unsigned short* __restrict__ Acat_g,
                const unsigned short* __restrict__ Wp_c, const unsigned short* __restrict__ Wp_g,
                const float* __restrict__ bias_c, const float* __restrict__ bias_g,
                const float* __restrict__ ls_c, const float* __restrict__ lb_c,
                const float* __restrict__ ls_g, const float* __restrict__ lb_g,
                unsigned short* __restrict__ outh_c, unsigned short* __restrict__ outh_g,
                float* __restrict__ outf_c, float* __restrict__ outf_g,
                int cellBlocks) {
    const unsigned short *A, *Wp; const float *bias, *lns, *lnb;
    unsigned short* outh; float* outf; int M, mb;
    if ((int)blockIdx.x < cellBlocks) {
        A = Acat_c; Wp = Wp_c; bias = bias_c; lns = ls_c; lnb = lb_c;
        outh = outh_c; outf = outf_c; M = NCELL; mb = blockIdx.x;
    } else {
        A = Acat_g; Wp = Wp_g; bias = bias_g; lns = ls_g; lnb = lb_g;
        outh = outh_g; outf = outf_g; M = NGENE; mb = blockIdx.x - cellBlocks;
    }
    __shared__ unsigned short Ws[32768];  // 64 KB
    int tid = threadIdx.x;
    {
        const uint4* s = (const uint4*)Wp;
        uint4* d = (uint4*)Ws;
        #pragma unroll
        for (int i = tid; i < 4096; i += 256) d[i] = s[i];
    }
    __syncthreads();

    int wave = tid >> 6, lane = tid & 63;
    int col0 = lane & 15;
    int kq = lane >> 4;
    int m_base = mb * GBM + wave * 32;

    f32x4 acc[2][8];
    #pragma unroll
    for (int mt = 0; mt < 2; ++mt)
        #pragma unroll
        for (int t = 0; t < 8; ++t) acc[mt][t] = (f32x4){0.f, 0.f, 0.f, 0.f};

    const unsigned short* Ar0 = A + (size_t)(m_base + col0) * 256 + kq * 8;
    const unsigned short* Ar1 = Ar0 + 16 * 256;
    #pragma unroll
    for (int c = 0; c < 8; ++c) {
        bf16x8 a0 = *(const bf16x8*)(Ar0 + c * 32);
        bf16x8 a1 = *(const bf16x8*)(Ar1 + c * 32);
        #pragma unroll
        for (int t = 0; t < 8; ++t) {
            bf16x8 b = *(const bf16x8*)(Ws + ((t * 8 + c) * 64 + lane) * 8);
            acc[0][t] = __builtin_amdgcn_mfma_f32_16x16x32_bf16(a0, b, acc[0][t], 0, 0, 0);
            acc[1][t] = __builtin_amdgcn_mfma_f32_16x16x32_bf16(a1, b, acc[1][t], 0, 0, 0);
        }
    }

    float bias_r[8], s_r[8], b_r[8];
    #pragma unroll
    for (int t = 0; t < 8; ++t) {
        int col = t * 16 + col0;
        bias_r[t] = bias[col]; s_r[t] = lns[col]; b_r[t] = lnb[col];
    }
    #pragma unroll
    for (int mt = 0; mt < 2; ++mt) {
        #pragma unroll
        for (int r = 0; r < 4; ++r) {
            int row = m_base + mt * 16 + kq * 4 + r;
            float v[8]; float sum = 0.f, sq = 0.f;
            #pragma unroll
            for (int t = 0; t < 8; ++t) {
                float x = acc[mt][t][r] + bias_r[t];
                x = (x >= 0.f) ? x : SLOPE * x;
                v[t] = x; sum += x; sq += x * x;
            }
            #pragma unroll
            for (int ofs = 1; ofs <= 8; ofs <<= 1) {
                sum += __shfl_xor(sum, ofs);
                sq  += __shfl_xor(sq, ofs);
            }
            float mu = sum * (1.0f / 128.0f);
            float var = sq * (1.0f / 128.0f) - mu * mu;
            float rstd = rsqrtf(var + LN_EPS);
            if (row < M) {
                if (outh) {
                    #pragma unroll
                    for (int t = 0; t < 8; ++t)
                        outh[(size_t)row * 128 + t * 16 + col0] =
                            f2bf((v[t] - mu) * rstd * s_r[t] + b_r[t]);
                } else {
                    #pragma unroll
                    for (int t = 0; t < 8; ++t)
                        outf[(size_t)row * 128 + t * 16 + col0] =
                            (v[t] - mu) * rstd * s_r[t] + b_r[t];
                }
            }
        }
    }
}

extern "C" void kernel_launch(void* const* d_in, const int* in_sizes, int n_in,
                              void* d_out, int out_size, void* d_ws, size_t ws_size,
                              hipStream_t stream) {
    const float* h_cell = (const float*)d_in[0];
    const float* h_gene = (const float*)d_in[1];
    const int* src_cg = (const int*)d_in[2];
    const int* dst_cg = (const int*)d_in[3];
    const int* src_gc = (const int*)d_in[4];
    const int* dst_gc = (const int*)d_in[5];
    const int* src_cc = (const int*)d_in[6];
    const int* dst_cc = (const int*)d_in[7];
    const int* src_gg = (const int*)d_in[8];
    const int* dst_gg = (const int*)d_in[9];
    const float* W_cg = (const float*)d_in[10];
    const float* W_gc = (const float*)d_in[11];
    const float* W_cc = (const float*)d_in[12];
    const float* W_gg = (const float*)d_in[13];
    const float* b_cell = (const float*)d_in[14];
    const float* b_gene = (const float*)d_in[15];
    const float* ln_s_cell = (const float*)d_in[16];
    const float* ln_b_cell = (const float*)d_in[17];
    const float* ln_s_gene = (const float*)d_in[18];
    const float* ln_b_gene = (const float*)d_in[19];
    float* out = (float*)d_out;

    const int MPC = ((NCELL + GBM - 1) / GBM) * GBM;
    const int MPG = ((NGENE + GBM - 1) / GBM) * GBM;
    const int NB_C = (NCELL + 255) / 256;   // 391 bins (shift 8)
    const int NB_G = (NGENE + 15) / 16;     // 500 bins (shift 4)
    // fixed bin capacities: mean + >8 sigma (Poisson)
    const int CAP_GC = 4352;   // mean 3836
    const int CAP_CC = 3072;   // mean 2558
    const int CAP_CG = 3584;   // mean 3000
    const int CAP_GG = 768;    // mean 400

    char* wsb = (char*)d_ws;
    size_t off = 0;
    auto alloc = [&](size_t bytes) -> char* {
        char* p = wsb + off;
        off = (off + bytes + 255) & ~(size_t)255;
        return p;
    };
    unsigned short* Acat_c = (unsigned short*)alloc((size_t)MPC * 256 * 2);
    unsigned short* Acat_g = (unsigned short*)alloc((size_t)MPG * 256 * 2);
    unsigned short* hcb0 = (unsigned short*)alloc((size_t)NCELL * DIM * 2);
    unsigned short* hgb0 = (unsigned short*)alloc((size_t)NGENE * DIM * 2);
    unsigned short* hcb1 = (unsigned short*)alloc((size_t)NCELL * DIM * 2);
    unsigned short* hgb1 = (unsigned short*)alloc((size_t)NGENE * DIM * 2);
    unsigned short* Wp_cell = (unsigned short*)alloc(65536);
    unsigned short* Wp_gene = (unsigned short*)alloc(65536);
    int ndeg = 2 * NCELL + 2 * NGENE;
    int* degs = (int*)alloc((size_t)ndeg * 4);
    int* deg_gc = degs;
    int* deg_cc = degs + NCELL;
    int* deg_cg = degs + 2 * NCELL;
    int* deg_gg = degs + 2 * NCELL + NGENE;
    int* offs = (int*)alloc((size_t)ndeg * 4);
    int* off_gc = offs;
    int* off_cc = offs + NCELL;
    int* off_cg = offs + 2 * NCELL;
    int* off_gg = offs + 2 * NCELL + NGENE;
    int* bkt_gc = (int*)alloc((size_t)NB_C * CAP_GC * 4);
    int* bkt_cc = (int*)alloc((size_t)NB_C * CAP_CC * 4);
    int* bkt_cg = (int*)alloc((size_t)NB_G * CAP_CG * 4);
    int* bkt_gg = (int*)alloc((size_t)NB_G * CAP_GG * 4);
    unsigned* stg_gc = (unsigned*)alloc((size_t)NB_C * CAP_GC * 4);
    unsigned* stg_cc = (unsigned*)alloc((size_t)NB_C * CAP_CC * 4);
    unsigned* stg_cg = (unsigned*)alloc((size_t)NB_G * CAP_CG * 4);
    unsigned* stg_gg = (unsigned*)alloc((size_t)NB_G * CAP_GG * 4);
    int* binmem = (int*)alloc(4 * 512 * 4);

    // ---- input conversion + weight packing (fused) ----
    const int n2c = NCELL * DIM / 2, n2g = NGENE * DIM / 2;
    const int convCB = (n2c + 255) / 256;
    const int convGB = (n2g + 255) / 256;
    conv2_k<<<convCB + convGB, 256, 0, stream>>>(h_cell, hcb0, h_gene, hgb0, convCB, n2c, n2g);
    pack2_w_k<<<128, 64, 0, stream>>>(W_gc, W_cc, Wp_cell, W_cg, W_gg, Wp_gene);

    // ---- binned CSR build: fill (fixed-cap bins) + per-bin counting sort ----
    hipMemsetAsync(binmem, 0, 4 * 512 * 4, stream);
    const int nbk_gc = (NE_GC + 4095) / 4096;
    const int nbk_cc = (NE_CC + 4095) / 4096;
    const int nbk_cg = (NE_CG + 4095) / 4096;
    const int nbk_gg = (NE_GG + 4095) / 4096;
    auto mkrel = [&](const int* s, const int* d, int n, int shift, int nbins, int N, int cap,
                     int* deg, int* offg, int* bkt, int* bm, unsigned* stg,
                     int cblk0, int sblk0) {
        RelP r;
        r.src = s; r.dst = d; r.n = n; r.shift = shift; r.nbins = nbins; r.N = N; r.cap = cap;
        r.deg = deg; r.offg = offg; r.bkt = bkt;
        r.bcur = bm; r.stg = stg;
        r.cblk0 = cblk0; r.sblk0 = sblk0;
        return r;
    };
    RelP r0 = mkrel(src_gc, dst_gc, NE_GC, 8, NB_C, NCELL, CAP_GC, deg_gc, off_gc, bkt_gc,
                    binmem + 0 * 512, stg_gc, 0, 0);
    RelP r1 = mkrel(src_cc, dst_cc, NE_CC, 8, NB_C, NCELL, CAP_CC, deg_cc, off_cc, bkt_cc,
                    binmem + 1 * 512, stg_cc, nbk_gc, NB_C);
    RelP r2 = mkrel(src_cg, dst_cg, NE_CG, 4, NB_G, NGENE, CAP_CG, deg_cg, off_cg, bkt_cg,
                    binmem + 2 * 512, stg_cg, nbk_gc + nbk_cc, 2 * NB_C);
    RelP r3 = mkrel(src_gg, dst_gg, NE_GG, 4, NB_G, NGENE, CAP_GG, deg_gg, off_gg, bkt_gg,
                    binmem + 3 * 512, stg_gg, nbk_gc + nbk_cc + nbk_cg, 2 * NB_C + NB_G);
    const int cntBlocks = nbk_gc + nbk_cc + nbk_cg + nbk_gg;
    const int csrBlocks = 2 * NB_C + 2 * NB_G;
    bin_fill4_k<<<cntBlocks, 256, 0, stream>>>(r0, r1, r2, r3);
    bin_csr4_k<<<csrBlocks, 256, 0, stream>>>(r0, r1, r2, r3);

    // ---- two shared layers ----
    const int gatherCB = NCELL / 4;           // 25000
    const int gatherGB = (NGENE + 3) / 4;     // 2000
    const int gemmCB = MPC / GBM;             // 782
    const int gemmGB = MPG / GBM;             // 63
    const unsigned short* hc = hcb0;
    const unsigned short* hg = hgb0;
    for (int layer = 0; layer < 2; ++layer) {
        int final_ = (layer == 1);
        gather2_k<<<gatherCB + gatherGB, 256, 0, stream>>>(
            hc, hg,
            off_gc, deg_gc, bkt_gc, off_cc, deg_cc, bkt_cc,
            off_cg, deg_cg, bkt_cg, off_gg, deg_gg, bkt_gg,
            Acat_c, Acat_g, gatherCB);
        gemm2_ln_k<<<gemmCB + gemmGB, 256, 0, stream>>>(
            Acat_c, Acat_g, Wp_cell, Wp_gene, b_cell, b_gene,
            ln_s_cell, ln_b_cell, ln_s_gene, ln_b_gene,
            final_ ? nullptr : hcb1, final_ ? nullptr : hgb1,
            final_ ? out : nullptr, final_ ? out + (size_t)NCELL * DIM : nullptr,
            gemmCB);
        hc = hcb1;
        hg = hgb1;
    }
}